// Round 8
// baseline (2745.017 us; speedup 1.0000x reference)
//
#include <hip/hip_runtime.h>
#include <hip/hip_bf16.h>
#include <math.h>

typedef unsigned long long u64;
typedef __hip_bfloat16 bf16;
typedef __attribute__((ext_vector_type(8))) short bf16x8;
typedef __attribute__((ext_vector_type(4))) float f32x4;

#define L_ 2
#define B_ 32
#define N_ 225
#define M_ 1800
#define D_ 768
#define H_ 256
#define MID_ 128
#define EPS_ 1e-5f
#define DELTA_ 1e-3f

__device__ __forceinline__ u64 enc_key(float v, int idx) {
  unsigned u = __float_as_uint(v);
  u = (u & 0x80000000u) ? ~u : (u | 0x80000000u);
  return ((u64)u << 32) | (u64)(0x7FFFFFFFu - (unsigned)idx);
}

__device__ __forceinline__ short f2bs(float x) {
  __hip_bfloat16 h = __float2bfloat16(x);
  return *reinterpret_cast<short*>(&h);
}

// ---------------- norms ----------------
__global__ __launch_bounds__(256) void k_norms(const float* __restrict__ q,
                                               const float* __restrict__ p,
                                               float* __restrict__ qinv,
                                               float* __restrict__ pinv) {
  int row = blockIdx.x;
  const float* src;
  float* dst;
  if (row < B_ * N_) {
    src = q + (size_t)row * D_;
    dst = qinv + row;
  } else {
    int r = row - B_ * N_;
    src = p + (size_t)r * D_;
    dst = pinv + r;
  }
  float s = 0.f;
  for (int i = threadIdx.x; i < D_; i += 256) {
    float v = src[i];
    s = fmaf(v, v, s);
  }
  __shared__ float red[256];
  red[threadIdx.x] = s;
  __syncthreads();
  for (int off = 128; off > 0; off >>= 1) {
    if (threadIdx.x < off) red[threadIdx.x] += red[threadIdx.x + off];
    __syncthreads();
  }
  if (threadIdx.x == 0) {
    float n = sqrtf(red[0]);
    n = fmaxf(n, 1e-12f);
    *dst = 1.0f / n;
  }
}

// ---------------- sim via bf16 MFMA + max1/max2 tracking ----------------
// Block: (b, n-tile of 64). 4 waves, wave w owns 16 n-cols. m-loop over 15
// steps of 128. q staged once in frag-ready LDS (bf16, normalized); p staged
// per k-chunk [128][32] bf16 (normalized). D[row=m][col=n] per conv-verified
// fragment mapping. Rows with approx top-2 gap <= DELTA_ are flagged for
// exact f32 re-ranking (k_exact).
__global__ __launch_bounds__(256) void k_sim2(const float* __restrict__ q,
    const float* __restrict__ p, const float* __restrict__ qinv,
    const float* __restrict__ pinv, u64* __restrict__ keys,
    unsigned* __restrict__ flags) {
  const int b = blockIdx.y;
  const int n0 = blockIdx.x * 64;
  __shared__ __align__(16) short qf[24 * 4 * 64 * 8];  // 98304 B
  __shared__ __align__(16) short As[2][128][40];       // 20480 B
  const int t = threadIdx.x;
  const int lane = t & 63;
  const int w = t >> 6;
  const float* qb = q + (size_t)b * N_ * D_;
  const float* pb = p + (size_t)b * M_ * D_;

  // ---- stage q (normalized bf16) into frag-ready layout ----
#pragma unroll 4
  for (int i = 0; i < 24; ++i) {
    int slot = t + 256 * i;
    int ck = slot >> 8;
    int rg = (slot >> 6) & 3;
    int ln = slot & 63;
    int r = ln & 15, g = ln >> 4;
    int n = n0 + rg * 16 + r;
    int k = ck * 32 + g * 8;
    bf16x8 v = {0, 0, 0, 0, 0, 0, 0, 0};
    if (n < N_) {
      float qs = qinv[b * N_ + n];
      float4 a = *(const float4*)(qb + (size_t)n * D_ + k);
      float4 c = *(const float4*)(qb + (size_t)n * D_ + k + 4);
      v[0] = f2bs(a.x * qs); v[1] = f2bs(a.y * qs);
      v[2] = f2bs(a.z * qs); v[3] = f2bs(a.w * qs);
      v[4] = f2bs(c.x * qs); v[5] = f2bs(c.y * qs);
      v[6] = f2bs(c.z * qs); v[7] = f2bs(c.w * qs);
    }
    *(bf16x8*)&qf[slot * 8] = v;
  }
  __syncthreads();

  u64 key1 = 0;
  float k1v = -2.f, max2 = -2.f;
  const int srow = t >> 1;
  const int sch = (t & 1) * 16;
  const int lr = lane & 15;
  const int lg = lane >> 4;

  for (int ms = 0; ms < 15; ++ms) {
    const int m0 = ms * 128;
    const int mrow = m0 + srow;
    const bool mok = (mrow < M_);
    const float pv = mok ? pinv[b * M_ + mrow] : 0.f;
    const float* prow = pb + (size_t)mrow * D_;
    f32x4 acc[8];
#pragma unroll
    for (int i = 0; i < 8; ++i) acc[i] = (f32x4){0.f, 0.f, 0.f, 0.f};

    // prologue: stage chunk 0
    {
      float4 L0 = {0,0,0,0}, L1 = {0,0,0,0}, L2 = {0,0,0,0}, L3 = {0,0,0,0};
      if (mok) {
        L0 = *(const float4*)(prow + sch + 0);
        L1 = *(const float4*)(prow + sch + 4);
        L2 = *(const float4*)(prow + sch + 8);
        L3 = *(const float4*)(prow + sch + 12);
      }
      bf16x8 v0, v1;
      v0[0]=f2bs(L0.x*pv); v0[1]=f2bs(L0.y*pv); v0[2]=f2bs(L0.z*pv); v0[3]=f2bs(L0.w*pv);
      v0[4]=f2bs(L1.x*pv); v0[5]=f2bs(L1.y*pv); v0[6]=f2bs(L1.z*pv); v0[7]=f2bs(L1.w*pv);
      v1[0]=f2bs(L2.x*pv); v1[1]=f2bs(L2.y*pv); v1[2]=f2bs(L2.z*pv); v1[3]=f2bs(L2.w*pv);
      v1[4]=f2bs(L3.x*pv); v1[5]=f2bs(L3.y*pv); v1[6]=f2bs(L3.z*pv); v1[7]=f2bs(L3.w*pv);
      *(bf16x8*)&As[0][srow][sch] = v0;
      *(bf16x8*)&As[0][srow][sch + 8] = v1;
    }
    __syncthreads();

    for (int kc = 0; kc < 24; ++kc) {
      // issue loads for kc+1 early
      float4 L0 = {0,0,0,0}, L1 = {0,0,0,0}, L2 = {0,0,0,0}, L3 = {0,0,0,0};
      const bool have = (kc + 1 < 24);
      if (have && mok) {
        const float* src = prow + (kc + 1) * 32 + sch;
        L0 = *(const float4*)(src + 0);
        L1 = *(const float4*)(src + 4);
        L2 = *(const float4*)(src + 8);
        L3 = *(const float4*)(src + 12);
      }
      // frags + MFMA
      bf16x8 qfr = *(const bf16x8*)&qf[((kc * 4 + w) * 64 + lane) * 8];
      const int buf = kc & 1;
#pragma unroll
      for (int mg = 0; mg < 8; ++mg) {
        bf16x8 pa = *(const bf16x8*)&As[buf][mg * 16 + lr][lg * 8];
        acc[mg] = __builtin_amdgcn_mfma_f32_16x16x32_bf16(pa, qfr, acc[mg], 0, 0, 0);
      }
      // convert + write kc+1
      if (have) {
        bf16x8 v0, v1;
        v0[0]=f2bs(L0.x*pv); v0[1]=f2bs(L0.y*pv); v0[2]=f2bs(L0.z*pv); v0[3]=f2bs(L0.w*pv);
        v0[4]=f2bs(L1.x*pv); v0[5]=f2bs(L1.y*pv); v0[6]=f2bs(L1.z*pv); v0[7]=f2bs(L1.w*pv);
        v1[0]=f2bs(L2.x*pv); v1[1]=f2bs(L2.y*pv); v1[2]=f2bs(L2.z*pv); v1[3]=f2bs(L2.w*pv);
        v1[4]=f2bs(L3.x*pv); v1[5]=f2bs(L3.y*pv); v1[6]=f2bs(L3.z*pv); v1[7]=f2bs(L3.w*pv);
        *(bf16x8*)&As[buf ^ 1][srow][sch] = v0;
        *(bf16x8*)&As[buf ^ 1][srow][sch + 8] = v1;
      }
      __syncthreads();
    }

    // extract this m-step's sims and merge into running (key1, max2)
#pragma unroll
    for (int mg = 0; mg < 8; ++mg) {
#pragma unroll
      for (int r = 0; r < 4; ++r) {
        int m = m0 + mg * 16 + lg * 4 + r;
        if (m < M_) {
          float v = acc[mg][r];
          u64 k = enc_key(v, m);
          if (k > key1) {
            max2 = fmaxf(max2, k1v);
            key1 = k;
            k1v = v;
          } else if (v > max2) {
            max2 = v;
          }
        }
      }
    }
  }

  // cross-lane merge over the 4 lanes sharing each n-col (lane^16, lane^32)
#pragma unroll
  for (int off = 16; off <= 32; off <<= 1) {
    u64 ok = __shfl_xor(key1, off);
    float okv = __shfl_xor(k1v, off);
    float om2 = __shfl_xor(max2, off);
    if (ok > key1) {
      max2 = fmaxf(fmaxf(max2, om2), k1v);
      key1 = ok;
      k1v = okv;
    } else {
      max2 = fmaxf(fmaxf(max2, om2), okv);
    }
  }
  if (lane < 16) {
    int n = n0 + w * 16 + lane;
    if (n < N_) {
      int row = b * N_ + n;
      keys[row] = key1;
      flags[row] = (k1v - max2 <= DELTA_) ? 1u : 0u;
    }
  }
}

// ---------------- exact f32 re-rank of flagged rows ----------------
__global__ __launch_bounds__(256) void k_exact(const float* __restrict__ q,
    const float* __restrict__ p, const float* __restrict__ qinv,
    const float* __restrict__ pinv, const unsigned* __restrict__ flags,
    u64* __restrict__ keys) {
  const int row = blockIdx.x;
  if (flags[row] == 0) return;
  const int b = row / N_;
  __shared__ float qs[D_];
  __shared__ u64 wb[4];
  const int t = threadIdx.x;
  const float qn = qinv[row];
  for (int i = t; i < D_; i += 256) qs[i] = q[(size_t)row * D_ + i] * qn;
  __syncthreads();
  const int w = t >> 6, lane = t & 63;
  u64 best = 0;
  for (int i = 0; i < 450; ++i) {
    int m = w + 4 * i;
    const float* pr = p + ((size_t)b * M_ + m) * D_;
    float s = 0.f;
#pragma unroll
    for (int e = 0; e < 12; ++e)
      s = fmaf(qs[lane * 12 + e], pr[lane * 12 + e], s);
    for (int o = 32; o; o >>= 1) s += __shfl_xor(s, o);
    s *= pinv[b * M_ + m];
    u64 k = enc_key(s, m);
    if (k > best) best = k;
  }
  if (lane == 0) wb[w] = best;
  __syncthreads();
  if (t == 0) {
    u64 bb = wb[0];
    for (int i = 1; i < 4; ++i)
      if (wb[i] > bb) bb = wb[i];
    keys[row] = bb;
  }
}

__global__ void k_decode(const u64* __restrict__ keys, float* __restrict__ residual,
                         int* __restrict__ idxbuf, float* __restrict__ out_res,
                         float* __restrict__ out_idx) {
  int i = blockIdx.x * 256 + threadIdx.x;
  if (i >= B_ * N_) return;
  u64 k = keys[i];
  unsigned u = (unsigned)(k >> 32);
  unsigned bits = (u & 0x80000000u) ? (u & 0x7FFFFFFFu) : ~u;
  float v = __uint_as_float(bits);
  int idx = (int)(0x7FFFFFFFu - (unsigned)(k & 0xFFFFFFFFu));
  if (idx < 0) idx = 0;
  if (idx >= M_) idx = M_ - 1;
  float r = 1.0f - v;
  if (r != r) r = 0.f;
  residual[i] = r;
  idxbuf[i] = idx;
  out_res[i] = r;
  out_idx[i] = (float)idx;
}

// ---------------- ctx -> BN -> cmap (bf16 scratch, [B*N][D]) ----------------
__global__ __launch_bounds__(256) void k_cmap(const float* __restrict__ q,
    const float* __restrict__ p, const int* __restrict__ idxbuf,
    const float* __restrict__ g, const float* __restrict__ bb,
    const float* __restrict__ bm, const float* __restrict__ bv,
    bf16* __restrict__ cmap) {
  int bn = blockIdx.x;
  int b = bn / N_;
  int id = idxbuf[bn];
  if (id < 0) id = 0;
  if (id >= M_) id = M_ - 1;
  const float* qr = q + (size_t)bn * D_;
  const float* pr = p + ((size_t)b * M_ + id) * D_;
  for (int d = threadIdx.x; d < D_; d += 256) {
    float qv = qr[d], pv = pr[d];
    float c = qv + fabsf(qv - pv);
    float val = (c - bm[d]) * (g[d] * rsqrtf(bv[d] + EPS_)) + bb[d];
    cmap[(size_t)bn * D_ + d] = __float2bfloat16(val);
  }
}

// ---------------- weight reshapes to bf16 [cout][k] (MFMA B-staging layout) ----------------
__global__ void k_prepw(const float* __restrict__ lc1, const float* __restrict__ lt1,
                        const float* __restrict__ lc2, const float* __restrict__ lt2,
                        bf16* __restrict__ wt1, bf16* __restrict__ wtT1,
                        bf16* __restrict__ wt2, bf16* __restrict__ wtT2) {
  int i = blockIdx.x * 256 + threadIdx.x;
  const int n1 = 9 * D_ * H_;
  const int n2 = 4 * H_ * H_;
  const int n3 = 9 * H_ * MID_;
  const int n4 = 4 * MID_ * MID_;
  if (i < n1) {
    int co = i / 6912;
    int rem = i % 6912;
    int tap = rem / 768;
    int d = rem % 768;
    wt1[i] = __float2bfloat16(lc1[((size_t)co * D_ + d) * 9 + tap]);
  } else if (i < n1 + n2) {
    int j = i - n1;
    int ij = j >> 16;
    int co = (j >> 8) & 255;
    int ci = j & 255;
    wtT1[j] = __float2bfloat16(lt1[((size_t)ci * H_ + co) * 4 + ij]);
  } else if (i < n1 + n2 + n3) {
    int j = i - n1 - n2;
    int co = j / 2304;
    int rem = j % 2304;
    int tap = rem >> 8;
    int ci = rem & 255;
    wt2[j] = __float2bfloat16(lc2[((size_t)co * H_ + ci) * 9 + tap]);
  } else if (i < n1 + n2 + n3 + n4) {
    int j = i - n1 - n2 - n3;
    int ij = j >> 14;
    int co = (j >> 7) & 127;
    int ci = j & 127;
    wtT2[j] = __float2bfloat16(lt2[((size_t)ci * MID_ + co) * 4 + ij]);
  }
}

// ================= MFMA conv kernels (round-7, unchanged) =================
template <int SHW, int CIN, int COUT>
__global__ __launch_bounds__(256) void k_conv3x3_mfma(
    const bf16* __restrict__ in, const bf16* __restrict__ wt,
    const float* __restrict__ bg, const float* __restrict__ bbeta,
    const float* __restrict__ bm, const float* __restrict__ bv,
    bf16* __restrict__ outp) {
  constexpr int S = SHW * SHW;
  constexpr int K = 9 * CIN;
  constexpr int NS = K / 32;
  constexpr int CS = CIN / 32;
  const int b = blockIdx.z;
  const int s0 = blockIdx.x * 64;
  const int c0 = blockIdx.y * 64;
  __shared__ __align__(16) short As[2][64][40];
  __shared__ __align__(16) short Bs[2][64][40];
  const int t = threadIdx.x;
  const int lane = t & 63;
  const int wm = (t >> 7) & 1;
  const int wn = (t >> 6) & 1;
  const int srow = t >> 2;
  const int sch = (t & 3) * 8;
  const int s_sp = s0 + srow;
  const int sy0 = s_sp / SHW, sx0 = s_sp % SHW;
  const bf16* inb = in + (size_t)b * S * CIN;
  const bf16* wrow = wt + (size_t)(c0 + srow) * K;
  const int lr = lane & 15;
  const int lk = (lane >> 4) * 8;

  f32x4 acc00 = {0.f, 0.f, 0.f, 0.f}, acc01 = {0.f, 0.f, 0.f, 0.f};
  f32x4 acc10 = {0.f, 0.f, 0.f, 0.f}, acc11 = {0.f, 0.f, 0.f, 0.f};

  auto loadA = [&](int kt) -> bf16x8 {
    int tap = kt / CS;
    int c00 = (kt % CS) * 32;
    int dy = tap / 3 - 1, dx = tap % 3 - 1;
    int sy = sy0 + dy, sx = sx0 + dx;
    bf16x8 av = {0, 0, 0, 0, 0, 0, 0, 0};
    if (s_sp < S && sy >= 0 && sy < SHW && sx >= 0 && sx < SHW)
      av = *(const bf16x8*)(inb + (size_t)(sy * SHW + sx) * CIN + c00 + sch);
    return av;
  };

  {
    bf16x8 av = loadA(0);
    bf16x8 wv = *(const bf16x8*)(wrow + sch);
    *(bf16x8*)&As[0][srow][sch] = av;
    *(bf16x8*)&Bs[0][srow][sch] = wv;
  }
  __syncthreads();
  int cur = 0;
  for (int kt = 0; kt < NS; ++kt) {
    bf16x8 avn, wvn;
    if (kt + 1 < NS) {
      avn = loadA(kt + 1);
      wvn = *(const bf16x8*)(wrow + (kt + 1) * 32 + sch);
    }
    bf16x8 a0 = *(const bf16x8*)&As[cur][wm * 32 + lr][lk];
    bf16x8 a1 = *(const bf16x8*)&As[cur][wm * 32 + 16 + lr][lk];
    bf16x8 b0 = *(const bf16x8*)&Bs[cur][wn * 32 + lr][lk];
    bf16x8 b1 = *(const bf16x8*)&Bs[cur][wn * 32 + 16 + lr][lk];
    acc00 = __builtin_amdgcn_mfma_f32_16x16x32_bf16(a0, b0, acc00, 0, 0, 0);
    acc01 = __builtin_amdgcn_mfma_f32_16x16x32_bf16(a0, b1, acc01, 0, 0, 0);
    acc10 = __builtin_amdgcn_mfma_f32_16x16x32_bf16(a1, b0, acc10, 0, 0, 0);
    acc11 = __builtin_amdgcn_mfma_f32_16x16x32_bf16(a1, b1, acc11, 0, 0, 0);
    if (kt + 1 < NS) {
      *(bf16x8*)&As[cur ^ 1][srow][sch] = avn;
      *(bf16x8*)&Bs[cur ^ 1][srow][sch] = wvn;
    }
    __syncthreads();
    cur ^= 1;
  }

  auto emit = [&](const f32x4& a, int mi, int ni) {
    int c = c0 + wn * 32 + ni * 16 + lr;
    float sg = bg[c] * rsqrtf(bv[c] + EPS_);
    float sh = bbeta[c] - bm[c] * sg;
#pragma unroll
    for (int r = 0; r < 4; ++r) {
      int s = s0 + wm * 32 + mi * 16 + (lane >> 4) * 4 + r;
      if (s < S)
        outp[((size_t)b * S + s) * COUT + c] =
            __float2bfloat16(fmaxf(fmaf(a[r], sg, sh), 0.f));
    }
  };
  emit(acc00, 0, 0);
  emit(acc01, 0, 1);
  emit(acc10, 1, 0);
  emit(acc11, 1, 1);
}

template <int SHW, int C>
__global__ __launch_bounds__(256) void k_convT_mfma(
    const bf16* __restrict__ in, const bf16* __restrict__ wt,
    const float* __restrict__ bias, bf16* __restrict__ outp) {
  constexpr int S = SHW * SHW;
  constexpr int NS = C / 32;
  const int b = blockIdx.z;
  const int ij = blockIdx.y & 3;
  const int c0 = (blockIdx.y >> 2) * 64;
  const int s0 = blockIdx.x * 64;
  __shared__ __align__(16) short As[2][64][40];
  __shared__ __align__(16) short Bs[2][64][40];
  const int t = threadIdx.x;
  const int lane = t & 63;
  const int wm = (t >> 7) & 1;
  const int wn = (t >> 6) & 1;
  const int srow = t >> 2;
  const int sch = (t & 3) * 8;
  const int s_sp = s0 + srow;
  const bf16* arow = in + ((size_t)b * S + s_sp) * C;
  const bf16* wrow = wt + (size_t)ij * C * C + (size_t)(c0 + srow) * C;
  const int lr = lane & 15;
  const int lk = (lane >> 4) * 8;

  f32x4 acc00 = {0.f, 0.f, 0.f, 0.f}, acc01 = {0.f, 0.f, 0.f, 0.f};
  f32x4 acc10 = {0.f, 0.f, 0.f, 0.f}, acc11 = {0.f, 0.f, 0.f, 0.f};

  {
    bf16x8 av = {0, 0, 0, 0, 0, 0, 0, 0};
    if (s_sp < S) av = *(const bf16x8*)(arow + sch);
    bf16x8 wv = *(const bf16x8*)(wrow + sch);
    *(bf16x8*)&As[0][srow][sch] = av;
    *(bf16x8*)&Bs[0][srow][sch] = wv;
  }
  __syncthreads();
  int cur = 0;
  for (int kt = 0; kt < NS; ++kt) {
    bf16x8 avn = {0, 0, 0, 0, 0, 0, 0, 0}, wvn;
    if (kt + 1 < NS) {
      if (s_sp < S) avn = *(const bf16x8*)(arow + (kt + 1) * 32 + sch);
      wvn = *(const bf16x8*)(wrow + (kt + 1) * 32 + sch);
    }
    bf16x8 a0 = *(const bf16x8*)&As[cur][wm * 32 + lr][lk];
    bf16x8 a1 = *(const bf16x8*)&As[cur][wm * 32 + 16 + lr][lk];
    bf16x8 b0 = *(const bf16x8*)&Bs[cur][wn * 32 + lr][lk];
    bf16x8 b1 = *(const bf16x8*)&Bs[cur][wn * 32 + 16 + lr][lk];
    acc00 = __builtin_amdgcn_mfma_f32_16x16x32_bf16(a0, b0, acc00, 0, 0, 0);
    acc01 = __builtin_amdgcn_mfma_f32_16x16x32_bf16(a0, b1, acc01, 0, 0, 0);
    acc10 = __builtin_amdgcn_mfma_f32_16x16x32_bf16(a1, b0, acc10, 0, 0, 0);
    acc11 = __builtin_amdgcn_mfma_f32_16x16x32_bf16(a1, b1, acc11, 0, 0, 0);
    if (kt + 1 < NS) {
      *(bf16x8*)&As[cur ^ 1][srow][sch] = avn;
      *(bf16x8*)&Bs[cur ^ 1][srow][sch] = wvn;
    }
    __syncthreads();
    cur ^= 1;
  }

  auto emit = [&](const f32x4& a, int mi, int ni) {
    int c = c0 + wn * 32 + ni * 16 + lr;
    float bj = bias[c];
#pragma unroll
    for (int r = 0; r < 4; ++r) {
      int s = s0 + wm * 32 + mi * 16 + (lane >> 4) * 4 + r;
      if (s < S) {
        int oy = 2 * (s / SHW) + (ij >> 1);
        int ox = 2 * (s % SHW) + (ij & 1);
        outp[((size_t)b * 4 * S + (size_t)oy * (2 * SHW) + ox) * C + c] =
            __float2bfloat16(a[r] + bj);
      }
    }
  };
  emit(acc00, 0, 0);
  emit(acc01, 0, 1);
  emit(acc10, 1, 0);
  emit(acc11, 1, 1);
}

__global__ __launch_bounds__(256) void k_convT_fuse_mfma(
    const bf16* __restrict__ in, const bf16* __restrict__ wt,
    const float* __restrict__ w3, float* __restrict__ l2c) {
  constexpr int SHW = 30, C = 128, S = SHW * SHW;
  constexpr int NS = C / 32;
  const int b = blockIdx.z;
  const int ij = blockIdx.y & 3;
  const int c0 = (blockIdx.y >> 2) * 64;
  const int s0 = blockIdx.x * 64;
  __shared__ __align__(16) short As[2][64][40];
  __shared__ __align__(16) short Bs[2][64][40];
  __shared__ float red0[64][2];
  __shared__ float red1[64][2];
  const int t = threadIdx.x;
  const int lane = t & 63;
  const int wm = (t >> 7) & 1;
  const int wn = (t >> 6) & 1;
  const int srow = t >> 2;
  const int sch = (t & 3) * 8;
  const int s_sp = s0 + srow;
  const bf16* arow = in + ((size_t)b * S + s_sp) * C;
  const bf16* wrow = wt + (size_t)ij * C * C + (size_t)(c0 + srow) * C;
  const int lr = lane & 15;
  const int lk = (lane >> 4) * 8;

  f32x4 acc00 = {0.f, 0.f, 0.f, 0.f}, acc01 = {0.f, 0.f, 0.f, 0.f};
  f32x4 acc10 = {0.f, 0.f, 0.f, 0.f}, acc11 = {0.f, 0.f, 0.f, 0.f};

  {
    bf16x8 av = {0, 0, 0, 0, 0, 0, 0, 0};
    if (s_sp < S) av = *(const bf16x8*)(arow + sch);
    bf16x8 wv = *(const bf16x8*)(wrow + sch);
    *(bf16x8*)&As[0][srow][sch] = av;
    *(bf16x8*)&Bs[0][srow][sch] = wv;
  }
  __syncthreads();
  int cur = 0;
  for (int kt = 0; kt < NS; ++kt) {
    bf16x8 avn = {0, 0, 0, 0, 0, 0, 0, 0}, wvn;
    if (kt + 1 < NS) {
      if (s_sp < S) avn = *(const bf16x8*)(arow + (kt + 1) * 32 + sch);
      wvn = *(const bf16x8*)(wrow + (kt + 1) * 32 + sch);
    }
    bf16x8 a0 = *(const bf16x8*)&As[cur][wm * 32 + lr][lk];
    bf16x8 a1 = *(const bf16x8*)&As[cur][wm * 32 + 16 + lr][lk];
    bf16x8 b0 = *(const bf16x8*)&Bs[cur][wn * 32 + lr][lk];
    bf16x8 b1 = *(const bf16x8*)&Bs[cur][wn * 32 + 16 + lr][lk];
    acc00 = __builtin_amdgcn_mfma_f32_16x16x32_bf16(a0, b0, acc00, 0, 0, 0);
    acc01 = __builtin_amdgcn_mfma_f32_16x16x32_bf16(a0, b1, acc01, 0, 0, 0);
    acc10 = __builtin_amdgcn_mfma_f32_16x16x32_bf16(a1, b0, acc10, 0, 0, 0);
    acc11 = __builtin_amdgcn_mfma_f32_16x16x32_bf16(a1, b1, acc11, 0, 0, 0);
    if (kt + 1 < NS) {
      *(bf16x8*)&As[cur ^ 1][srow][sch] = avn;
      *(bf16x8*)&Bs[cur ^ 1][srow][sch] = wvn;
    }
    __syncthreads();
    cur ^= 1;
  }

  const float w0a = w3[c0 + wn * 32 + lr];
  const float w0b = w3[c0 + wn * 32 + 16 + lr];
  const float w1a = w3[MID_ + c0 + wn * 32 + lr];
  const float w1b = w3[MID_ + c0 + wn * 32 + 16 + lr];
#pragma unroll
  for (int mi = 0; mi < 2; ++mi) {
    f32x4 aa0 = mi ? acc10 : acc00;
    f32x4 aa1 = mi ? acc11 : acc01;
#pragma unroll
    for (int r = 0; r < 4; ++r) {
      float p0 = aa0[r] * w0a + aa1[r] * w0b;
      float p1 = aa0[r] * w1a + aa1[r] * w1b;
      p0 += __shfl_xor(p0, 1); p0 += __shfl_xor(p0, 2);
      p0 += __shfl_xor(p0, 4); p0 += __shfl_xor(p0, 8);
      p1 += __shfl_xor(p1, 1); p1 += __shfl_xor(p1, 2);
      p1 += __shfl_xor(p1, 4); p1 += __shfl_xor(p1, 8);
      if (lr == 0) {
        int rl = wm * 32 + mi * 16 + (lane >> 4) * 4 + r;
        red0[rl][wn] = p0;
        red1[rl][wn] = p1;
      }
    }
  }
  __syncthreads();
  if (t < 64) {
    int s = s0 + t;
    if (s < S) {
      float v0 = red0[t][0] + red0[t][1];
      float v1 = red1[t][0] + red1[t][1];
      int oy = 2 * (s / SHW) + (ij >> 1);
      int ox = 2 * (s % SHW) + (ij & 1);
      int opix = oy * 60 + ox;
      atomicAdd(&l2c[(size_t)b * 7200 + opix], v0);
      atomicAdd(&l2c[(size_t)b * 7200 + 3600 + opix], v1);
    }
  }
}

// ---------------- l2c init ----------------
__global__ void k_l2cinit(const float* __restrict__ lt2b, const float* __restrict__ w3,
                          const float* __restrict__ b3, float* __restrict__ l2c) {
  __shared__ float ini[2];
  int t = threadIdx.x;
  if (t < 2) {
    float s = b3[t];
    for (int ci = 0; ci < MID_; ++ci) s = fmaf(lt2b[ci], w3[t * MID_ + ci], s);
    ini[t] = s;
  }
  __syncthreads();
  int i = blockIdx.x * 256 + t;
  if (i < 7200) l2c[(size_t)blockIdx.y * 7200 + i] = ini[i / 3600];
}

// ---------------- patch head ----------------
__global__ __launch_bounds__(256) void k_patch(const float* __restrict__ l2c,
    const float* __restrict__ residual, float* __restrict__ out_ev,
    float* __restrict__ out_pl) {
  const int b = blockIdx.x;
  __shared__ float sm0[3600];
  __shared__ float sm1[3600];
  for (int i = threadIdx.x; i < 3600; i += 256) {
    sm0[i] = l2c[(size_t)b * 7200 + i];
    sm1[i] = l2c[(size_t)b * 7200 + 3600 + i];
  }
  __syncthreads();
  const int t = threadIdx.x;
  if (t >= 225) return;
  const int py = t / 15, px = t % 15;
  const float cy = 16.f * py + 7.5f;
  const float cx = 16.f * px + 7.5f;
  const int ky_lo = max(0, 16 * py - 8), ky_hi = min(239, 16 * py + 23);
  const int kx_lo = max(0, 16 * px - 8), kx_hi = min(239, 16 * px + 23);
  float acc0 = 0.f, acc1 = 0.f, wsum = 0.f;
  for (int ky = ky_lo; ky <= ky_hi; ++ky) {
    float wy = 1.f - fabsf((float)ky - cy) * 0.0625f;
    float c60y = 0.25f * ky - 0.375f;
    int jy = (int)floorf(c60y);
    float fy = c60y - (float)jy;
    int jy0 = max(jy, 0), jy1 = min(jy + 1, 59);
    for (int kx = kx_lo; kx <= kx_hi; ++kx) {
      float wx = 1.f - fabsf((float)kx - cx) * 0.0625f;
      float w = wy * wx;
      float c60x = 0.25f * kx - 0.375f;
      int jx = (int)floorf(c60x);
      float fx = c60x - (float)jx;
      int jx0 = max(jx, 0), jx1 = min(jx + 1, 59);
      float v0 = (1.f - fy) * ((1.f - fx) * sm0[jy0 * 60 + jx0] + fx * sm0[jy0 * 60 + jx1])
               + fy * ((1.f - fx) * sm0[jy1 * 60 + jx0] + fx * sm0[jy1 * 60 + jx1]);
      float v1 = (1.f - fy) * ((1.f - fx) * sm1[jy0 * 60 + jx0] + fx * sm1[jy0 * 60 + jx1])
               + fy * ((1.f - fx) * sm1[jy1 * 60 + jx0] + fx * sm1[jy1 * 60 + jx1]);
      acc0 = fmaf(w, v0, acc0);
      acc1 = fmaf(w, v1, acc1);
      wsum += w;
    }
  }
  float p0 = acc0 / wsum, p1 = acc1 / wsum;
  float logit = p1 - p0;
  float score1 = 1.0f / (1.0f + expf(p0 - p1));
  float ev = 0.5f * residual[b * N_ + t] + 0.5f * score1;
  out_pl[b * N_ + t] = logit;
  out_ev[b * N_ + t] = ev;
}

// ---------------- upsample 60->240 bilinear ----------------
__global__ __launch_bounds__(256) void k_up(const float* __restrict__ l2c,
                                            float* __restrict__ out_l2c,
                                            float* __restrict__ out_ls) {
  const int b = blockIdx.y;
  const int pix = blockIdx.x * 256 + threadIdx.x;
  const int y = pix / 240, x = pix % 240;
  float sy = 0.25f * y - 0.375f;
  int ky = (int)floorf(sy);
  float fy = sy - (float)ky;
  float sx = 0.25f * x - 0.375f;
  int kx = (int)floorf(sx);
  float fx = sx - (float)kx;
  int ky0 = max(ky, 0), ky1 = min(ky + 1, 59);
  int kx0 = max(kx, 0), kx1 = min(kx + 1, 59);
  float v[2];
#pragma unroll
  for (int c = 0; c < 2; ++c) {
    const float* base = l2c + ((size_t)b * 2 + c) * 3600;
    float top = (1.f - fx) * base[ky0 * 60 + kx0] + fx * base[ky0 * 60 + kx1];
    float bot = (1.f - fx) * base[ky1 * 60 + kx0] + fx * base[ky1 * 60 + kx1];
    v[c] = (1.f - fy) * top + fy * bot;
  }
  float s1 = 1.f / (1.f + expf(v[0] - v[1]));
  float s0 = 1.f / (1.f + expf(v[1] - v[0]));
  size_t o0 = ((size_t)b * 2 + 0) * 57600 + pix;
  size_t o1 = ((size_t)b * 2 + 1) * 57600 + pix;
  out_l2c[o0] = v[0];
  out_l2c[o1] = v[1];
  out_ls[o0] = s0;
  out_ls[o1] = s1;
}

// ---------------- fusion stats ----------------
__global__ __launch_bounds__(256) void k_fusion(const bf16* __restrict__ cmap,
                                                float* __restrict__ gfeat) {
  int wid = ((blockIdx.x * 256 + threadIdx.x) >> 6);
  int lane = threadIdx.x & 63;
  if (wid >= B_ * D_) return;
  int b = wid / D_, d = wid % D_;
  const bf16* base = cmap + (size_t)b * N_ * D_ + d;
  float v[4];
  bool alive[4];
  float sum = 0.f;
#pragma unroll
  for (int r = 0; r < 4; ++r) {
    int n = lane + r * 64;
    bool ok = (n < N_);
    v[r] = ok ? __bfloat162float(base[(size_t)n * D_]) : -INFINITY;
    alive[r] = ok;
    if (ok) sum += v[r];
  }
  for (int o = 32; o > 0; o >>= 1) sum += __shfl_xor(sum, o);
  float topsum = 0.f;
  for (int it = 0; it < 10; ++it) {
    float lm = -INFINITY;
    int ls = -1;
#pragma unroll
    for (int r = 0; r < 4; ++r)
      if (alive[r] && v[r] > lm) { lm = v[r]; ls = r; }
    float wm = lm;
    for (int o = 32; o > 0; o >>= 1) wm = fmaxf(wm, __shfl_xor(wm, o));
    topsum += wm;
    u64 ball = __ballot(lm == wm);
    int owner = __ffsll((long long)ball) - 1;
    if (lane == owner && ls >= 0) alive[ls] = false;
  }
  if (lane == 0) gfeat[wid] = 0.5f * (sum / 225.0f + topsum * 0.1f);
}

// ---------------- fused FC head ----------------
__global__ __launch_bounds__(256) void k_fc(const float* __restrict__ gfeat,
    const float* __restrict__ g1w, const float* __restrict__ bg1,
    const float* __restrict__ bb1, const float* __restrict__ bm1,
    const float* __restrict__ bv1, const float* __restrict__ g2w,
    const float* __restrict__ bg2, const float* __restrict__ bb2,
    const float* __restrict__ bm2, const float* __restrict__ bv2,
    const float* __restrict__ g3w, float* __restrict__ out_gl,
    float* __restrict__ out_g2c) {
  __shared__ float gf[D_];
  __shared__ float h1s[H_];
  __shared__ float h2s[MID_];
  __shared__ float g2cs[2];
  const int b = blockIdx.x;
  const int t = threadIdx.x;
  for (int i = t; i < D_; i += 256) gf[i] = gfeat[b * D_ + i];
  __syncthreads();
  {
    float a = 0.f;
    const float* w = g1w + (size_t)t * D_;
    for (int d = 0; d < D_; ++d) a = fmaf(gf[d], w[d], a);
    float s = bg1[t] * rsqrtf(bv1[t] + EPS_);
    h1s[t] = fmaxf((a - bm1[t]) * s + bb1[t], 0.f);
  }
  __syncthreads();
  if (t < MID_) {
    float a = 0.f;
    const float* w = g2w + (size_t)t * H_;
    for (int k = 0; k < H_; ++k) a = fmaf(h1s[k], w[k], a);
    float s = bg2[t] * rsqrtf(bv2[t] + EPS_);
    h2s[t] = fmaxf((a - bm2[t]) * s + bb2[t], 0.f);
  }
  __syncthreads();
  if (t < 2) {
    float a = 0.f;
    const float* w = g3w + (size_t)t * MID_;
    for (int k = 0; k < MID_; ++k) a = fmaf(h2s[k], w[k], a);
    g2cs[t] = a;
    out_g2c[b * 2 + t] = a;
  }
  __syncthreads();
  if (t == 0) out_gl[b] = g2cs[1] - g2cs[0];
}

// ================= host =================
extern "C" void kernel_launch(void* const* d_in, const int* in_sizes, int n_in,
                              void* d_out, int out_size, void* d_ws, size_t ws_size,
                              hipStream_t stream) {
  (void)in_sizes; (void)n_in; (void)out_size; (void)ws_size;
  const float* query = (const float*)d_in[0];
  const float* prompt = (const float*)d_in[1];
  const float* bns_g = (const float*)d_in[2];
  const float* bns_b = (const float*)d_in[3];
  const float* bns_m = (const float*)d_in[4];
  const float* bns_v = (const float*)d_in[5];
  const float* lc1_w = (const float*)d_in[6];
  const float* lbn1_g = (const float*)d_in[7];
  const float* lbn1_b = (const float*)d_in[8];
  const float* lbn1_m = (const float*)d_in[9];
  const float* lbn1_v = (const float*)d_in[10];
  const float* lt1_w = (const float*)d_in[11];
  const float* lt1_b = (const float*)d_in[12];
  const float* lc2_w = (const float*)d_in[13];
  const float* lbn2_g = (const float*)d_in[14];
  const float* lbn2_b = (const float*)d_in[15];
  const float* lbn2_m = (const float*)d_in[16];
  const float* lbn2_v = (const float*)d_in[17];
  const float* lt2_w = (const float*)d_in[18];
  const float* lt2_b = (const float*)d_in[19];
  const float* lc3_w = (const float*)d_in[20];
  const float* lc3_b = (const float*)d_in[21];
  const float* g1_w = (const float*)d_in[22];
  const float* gbn1_g = (const float*)d_in[23];
  const float* gbn1_b = (const float*)d_in[24];
  const float* gbn1_m = (const float*)d_in[25];
  const float* gbn1_v = (const float*)d_in[26];
  const float* g2_w = (const float*)d_in[27];
  const float* gbn2_g = (const float*)d_in[28];
  const float* gbn2_b = (const float*)d_in[29];
  const float* gbn2_m = (const float*)d_in[30];
  const float* gbn2_v = (const float*)d_in[31];
  const float* g3_w = (const float*)d_in[32];

  float* ob = (float*)d_out;  // output is float32
  char* ob_c = (char*)d_out;
  char* ws = (char*)d_ws;
  // --- workspace (~7.2 MB) ---
  u64* keys = (u64*)(ws + 0);                    // 57,600 B
  float* qinv = (float*)(ws + 57600);            // 28,800
  float* pinv = (float*)(ws + 86400);            // 230,400
  float* residual = (float*)(ws + 316800);       // 57,600
  int* idxbuf = (int*)(ws + 374400);             // 28,800
  float* gfeat = (float*)(ws + 403200);          // 98,304
  float* l2c = (float*)(ws + 501504);            // 1,843,200
  bf16* wt1 = (bf16*)(ws + 2344704);             // 3,538,944
  bf16* wtT1 = (bf16*)(ws + 5883648);            // 524,288
  bf16* wt2 = (bf16*)(ws + 6407936);             // 589,824
  bf16* wtT2 = (bf16*)(ws + 6997760);            // 131,072
  unsigned* flags = (unsigned*)(ws + 7128832);   // 28,800 -> end 7,157,632

  // output offsets in f32 elements (return order: ev, pl, gl, g2c, l2c, ls, res, idx)
  const size_t OFF_EV = 0;
  const size_t OFF_PL = 14400;
  const size_t OFF_GL = 28800;
  const size_t OFF_G2C = 28864;
  const size_t OFF_L2C = 28992;
  const size_t OFF_LS = 7401792;
  const size_t OFF_RES = 14774592;
  const size_t OFF_IDX = 14788992;

  // bf16 conv scratch packed into the BYTE range of the l2c/ls chunks
  bf16* cmap = (bf16*)(ob_c + 115968);
  bf16* x1 = (bf16*)(ob_c + 11175168);
  bf16* y1 = (bf16*)(ob_c + 14861568);
  bf16* x2 = (bf16*)(ob_c + 29607168);

  // ---------- phase A ----------
  for (int l = 0; l < L_; ++l) {
    const float* q = query + (size_t)l * B_ * N_ * D_;
    const float* p = prompt + (size_t)l * B_ * M_ * D_;
    float* out_gl = ob + OFF_GL + (size_t)l * B_;
    float* out_g2c = ob + OFF_G2C + (size_t)l * B_ * 2;
    float* out_res = ob + OFF_RES + (size_t)l * B_ * N_;
    float* out_idx = ob + OFF_IDX + (size_t)l * B_ * N_;
    float* res_l = residual + (size_t)l * B_ * N_;
    float* l2c_l = l2c + (size_t)l * B_ * 7200;

    k_norms<<<dim3(B_ * (N_ + M_)), dim3(256), 0, stream>>>(q, p, qinv, pinv);
    k_sim2<<<dim3(4, B_), dim3(256), 0, stream>>>(q, p, qinv, pinv, keys, flags);
    k_exact<<<dim3(B_ * N_), dim3(256), 0, stream>>>(q, p, qinv, pinv, flags, keys);
    k_decode<<<dim3(29), dim3(256), 0, stream>>>(keys, res_l, idxbuf, out_res, out_idx);
    k_cmap<<<dim3(B_ * N_), dim3(256), 0, stream>>>(q, p, idxbuf,
        bns_g + l * D_, bns_b + l * D_, bns_m + l * D_, bns_v + l * D_, cmap);
    k_fusion<<<dim3(B_ * D_ / 4), dim3(256), 0, stream>>>(cmap, gfeat);
    k_fc<<<dim3(B_), dim3(256), 0, stream>>>(gfeat,
        g1_w + (size_t)l * H_ * D_, gbn1_g + l * H_, gbn1_b + l * H_, gbn1_m + l * H_, gbn1_v + l * H_,
        g2_w + (size_t)l * MID_ * H_, gbn2_g + l * MID_, gbn2_b + l * MID_, gbn2_m + l * MID_, gbn2_v + l * MID_,
        g3_w + (size_t)l * 2 * MID_, out_gl, out_g2c);
    k_prepw<<<dim3(9344), dim3(256), 0, stream>>>(
        lc1_w + (size_t)l * H_ * D_ * 9, lt1_w + (size_t)l * H_ * H_ * 4,
        lc2_w + (size_t)l * MID_ * H_ * 9, lt2_w + (size_t)l * MID_ * MID_ * 4,
        wt1, wtT1, wt2, wtT2);
    k_l2cinit<<<dim3(29, B_), dim3(256), 0, stream>>>(lt2_b + l * MID_,
        lc3_w + (size_t)l * 2 * MID_, lc3_b + l * 2, l2c_l);
    k_conv3x3_mfma<15, 768, 256><<<dim3(4, 4, B_), dim3(256), 0, stream>>>(cmap, wt1,
        lbn1_g + l * H_, lbn1_b + l * H_, lbn1_m + l * H_, lbn1_v + l * H_, x1);
    k_convT_mfma<15, 256><<<dim3(4, 16, B_), dim3(256), 0, stream>>>(x1, wtT1,
        lt1_b + l * H_, y1);
    k_conv3x3_mfma<30, 256, 128><<<dim3(15, 2, B_), dim3(256), 0, stream>>>(y1, wt2,
        lbn2_g + l * MID_, lbn2_b + l * MID_, lbn2_m + l * MID_, lbn2_v + l * MID_, x2);
    k_convT_fuse_mfma<<<dim3(15, 8, B_), dim3(256), 0, stream>>>(x2, wtT2,
        lc3_w + (size_t)l * 2 * MID_, l2c_l);
  }

  // ---------- phase B ----------
  for (int l = 0; l < L_; ++l) {
    float* out_ev = ob + OFF_EV + (size_t)l * B_ * N_;
    float* out_pl = ob + OFF_PL + (size_t)l * B_ * N_;
    float* out_l2c = ob + OFF_L2C + (size_t)l * B_ * 2 * 57600;
    float* out_ls = ob + OFF_LS + (size_t)l * B_ * 2 * 57600;
    float* res_l = residual + (size_t)l * B_ * N_;
    float* l2c_l = l2c + (size_t)l * B_ * 7200;
    k_patch<<<dim3(B_), dim3(256), 0, stream>>>(l2c_l, res_l, out_ev, out_pl);
    k_up<<<dim3(225, B_), dim3(256), 0, stream>>>(l2c_l, out_l2c, out_ls);
  }
}

// Round 10
// 1777.079 us; speedup vs baseline: 1.5447x; 1.5447x over previous
//
#include <hip/hip_runtime.h>
#include <hip/hip_bf16.h>
#include <math.h>

typedef unsigned long long u64;
typedef __hip_bfloat16 bf16;
typedef __attribute__((ext_vector_type(8))) short bf16x8;
typedef __attribute__((ext_vector_type(4))) float f32x4;

#define L_ 2
#define B_ 32
#define N_ 225
#define M_ 1800
#define D_ 768
#define H_ 256
#define MID_ 128
#define EPS_ 1e-5f
#define DELTA_ 1e-5f

__device__ __forceinline__ u64 enc_key(float v, int idx) {
  unsigned u = __float_as_uint(v);
  u = (u & 0x80000000u) ? ~u : (u | 0x80000000u);
  return ((u64)u << 32) | (u64)(0x7FFFFFFFu - (unsigned)idx);
}

__device__ __forceinline__ float dec_key(u64 k) {
  unsigned u = (unsigned)(k >> 32);
  unsigned bits = (u & 0x80000000u) ? (u & 0x7FFFFFFFu) : ~u;
  return __uint_as_float(bits);
}

__device__ __forceinline__ short f2bs(float x) {
  __hip_bfloat16 h = __float2bfloat16(x);
  return *reinterpret_cast<short*>(&h);
}

// convert 8 normalized floats to hi/lo bf16 pairs
__device__ __forceinline__ void cvt8(const float4& A, const float4& Bv, float nv,
                                     bf16x8& hi, bf16x8& lo) {
  float x[8] = {A.x * nv, A.y * nv, A.z * nv, A.w * nv,
                Bv.x * nv, Bv.y * nv, Bv.z * nv, Bv.w * nv};
#pragma unroll
  for (int e = 0; e < 8; ++e) {
    short h = f2bs(x[e]);
    float hf = __uint_as_float(((unsigned)(unsigned short)h) << 16);
    hi[e] = h;
    lo[e] = f2bs(x[e] - hf);
  }
}

// ---------------- norms ----------------
__global__ __launch_bounds__(256) void k_norms(const float* __restrict__ q,
                                               const float* __restrict__ p,
                                               float* __restrict__ qinv,
                                               float* __restrict__ pinv) {
  int row = blockIdx.x;
  const float* src;
  float* dst;
  if (row < B_ * N_) {
    src = q + (size_t)row * D_;
    dst = qinv + row;
  } else {
    int r = row - B_ * N_;
    src = p + (size_t)r * D_;
    dst = pinv + r;
  }
  float s = 0.f;
  for (int i = threadIdx.x; i < D_; i += 256) {
    float v = src[i];
    s = fmaf(v, v, s);
  }
  __shared__ float red[256];
  red[threadIdx.x] = s;
  __syncthreads();
  for (int off = 128; off > 0; off >>= 1) {
    if (threadIdx.x < off) red[threadIdx.x] += red[threadIdx.x + off];
    __syncthreads();
  }
  if (threadIdx.x == 0) {
    float n = sqrtf(red[0]);
    n = fmaxf(n, 1e-12f);
    *dst = 1.0f / n;
  }
}

// ---------------- split-bf16 sim: block = (m-tile 128) x (all 240 n) ----------------
// 3 MFMAs per frag (hi*hi + hi*lo + lo*hi): sim error ~1.5e-7. Per-block
// partial (top1 key, max2) written per row; k_reduce merges 15 partials.
__global__ __launch_bounds__(256, 2) void k_sim3(const float* __restrict__ q,
    const float* __restrict__ p, const float* __restrict__ qinv,
    const float* __restrict__ pinv, u64* __restrict__ pkeys,
    float* __restrict__ pmax2) {
  const int mt = blockIdx.x;
  const int b = blockIdx.y;
  const int m0 = mt * 128;
  __shared__ __align__(16) short Ph[128][40];
  __shared__ __align__(16) short Pl[128][40];
  __shared__ __align__(16) short Qh[256][40];
  __shared__ __align__(16) short Ql[256][40];
  const int t = threadIdx.x;
  const int lane = t & 63;
  const int w = t >> 6;
  const int lr = lane & 15;
  const int lg = lane >> 4;
  const float* qb = q + (size_t)b * N_ * D_;
  const float* pb = p + (size_t)b * M_ * D_;

  f32x4 acc[8][4];
#pragma unroll
  for (int mg = 0; mg < 8; ++mg)
#pragma unroll
    for (int ng = 0; ng < 4; ++ng) acc[mg][ng] = (f32x4){0.f, 0.f, 0.f, 0.f};

  for (int kc = 0; kc < 24; ++kc) {
    const int k0 = kc * 32;
    __syncthreads();  // previous MFMA phase done reading LDS
    // stage p (128 rows x 32 k): 512 groups of 8  [BUGFIX: was 4 iters -> OOB into Pl]
#pragma unroll
    for (int i = 0; i < 2; ++i) {
      int g = t + 256 * i;
      int row = g >> 2, koff = (g & 3) * 8;
      int m = m0 + row;
      float4 A = {0, 0, 0, 0}, Bv = {0, 0, 0, 0};
      float nv = 0.f;
      if (m < M_) {
        nv = pinv[b * M_ + m];
        const float* src = pb + (size_t)m * D_ + k0 + koff;
        A = *(const float4*)src;
        Bv = *(const float4*)(src + 4);
      }
      bf16x8 hi, lo;
      cvt8(A, Bv, nv, hi, lo);
      *(bf16x8*)&Ph[row][koff] = hi;
      *(bf16x8*)&Pl[row][koff] = lo;
    }
    // stage q (256 rows x 32 k, rows >=225 zero): 1024 groups of 8
#pragma unroll
    for (int i = 0; i < 4; ++i) {
      int g = t + 256 * i;
      int row = g >> 2, koff = (g & 3) * 8;
      float4 A = {0, 0, 0, 0}, Bv = {0, 0, 0, 0};
      float nv = 0.f;
      if (row < N_) {
        nv = qinv[b * N_ + row];
        const float* src = qb + (size_t)row * D_ + k0 + koff;
        A = *(const float4*)src;
        Bv = *(const float4*)(src + 4);
      }
      bf16x8 hi, lo;
      cvt8(A, Bv, nv, hi, lo);
      *(bf16x8*)&Qh[row][koff] = hi;
      *(bf16x8*)&Ql[row][koff] = lo;
    }
    __syncthreads();
    // MFMA: wave w owns n-frags w*4 .. w*4+3
    bf16x8 qh[4], ql[4];
#pragma unroll
    for (int ng = 0; ng < 4; ++ng) {
      int nrow = (w * 4 + ng) * 16 + lr;
      qh[ng] = *(const bf16x8*)&Qh[nrow][lg * 8];
      ql[ng] = *(const bf16x8*)&Ql[nrow][lg * 8];
    }
#pragma unroll
    for (int mg = 0; mg < 8; ++mg) {
      bf16x8 ph = *(const bf16x8*)&Ph[mg * 16 + lr][lg * 8];
      bf16x8 pl = *(const bf16x8*)&Pl[mg * 16 + lr][lg * 8];
#pragma unroll
      for (int ng = 0; ng < 4; ++ng) {
        acc[mg][ng] = __builtin_amdgcn_mfma_f32_16x16x32_bf16(pl, qh[ng], acc[mg][ng], 0, 0, 0);
        acc[mg][ng] = __builtin_amdgcn_mfma_f32_16x16x32_bf16(ph, ql[ng], acc[mg][ng], 0, 0, 0);
        acc[mg][ng] = __builtin_amdgcn_mfma_f32_16x16x32_bf16(ph, qh[ng], acc[mg][ng], 0, 0, 0);
      }
    }
  }

  // extract per-ng top1/max2 over this block's 128 m-rows
  u64 key1[4];
  float k1v[4], max2[4];
#pragma unroll
  for (int ng = 0; ng < 4; ++ng) { key1[ng] = 0; k1v[ng] = -2.f; max2[ng] = -2.f; }
#pragma unroll
  for (int ng = 0; ng < 4; ++ng) {
#pragma unroll
    for (int mg = 0; mg < 8; ++mg) {
#pragma unroll
      for (int r = 0; r < 4; ++r) {
        int m = m0 + mg * 16 + lg * 4 + r;
        if (m < M_) {
          float v = acc[mg][ng][r];
          u64 k = enc_key(v, m);
          if (k > key1[ng]) {
            max2[ng] = fmaxf(max2[ng], k1v[ng]);
            key1[ng] = k;
            k1v[ng] = v;
          } else if (v > max2[ng]) {
            max2[ng] = v;
          }
        }
      }
    }
  }
  // cross-lg merge (lane^16, lane^32) and write partials
#pragma unroll
  for (int ng = 0; ng < 4; ++ng) {
#pragma unroll
    for (int off = 16; off <= 32; off <<= 1) {
      u64 ok = __shfl_xor(key1[ng], off);
      float okv = __shfl_xor(k1v[ng], off);
      float om2 = __shfl_xor(max2[ng], off);
      if (ok > key1[ng]) {
        max2[ng] = fmaxf(fmaxf(max2[ng], om2), k1v[ng]);
        key1[ng] = ok;
        k1v[ng] = okv;
      } else {
        max2[ng] = fmaxf(fmaxf(max2[ng], om2), okv);
      }
    }
    if (lg == 0) {
      int n = (w * 4 + ng) * 16 + lr;
      if (n < N_) {
        size_t idx = (size_t)mt * (B_ * N_) + b * N_ + n;
        pkeys[idx] = key1[ng];
        pmax2[idx] = max2[ng];
      }
    }
  }
}

// ---------------- merge 15 partials per row -> keys + flag ----------------
__global__ void k_reduce(const u64* __restrict__ pkeys, const float* __restrict__ pmax2,
                         u64* __restrict__ keys, unsigned* __restrict__ flags) {
  int row = blockIdx.x * 256 + threadIdx.x;
  if (row >= B_ * N_) return;
  u64 key1 = 0;
  float k1v = -2.f, max2 = -2.f;
  for (int mt = 0; mt < 15; ++mt) {
    u64 k = pkeys[(size_t)mt * (B_ * N_) + row];
    float m2 = pmax2[(size_t)mt * (B_ * N_) + row];
    float kv = dec_key(k);
    if (k > key1) {
      max2 = fmaxf(fmaxf(max2, m2), k1v);
      key1 = k;
      k1v = kv;
    } else {
      max2 = fmaxf(fmaxf(max2, m2), kv);
    }
  }
  keys[row] = key1;
  flags[row] = (k1v - max2 <= DELTA_) ? 1u : 0u;
}

// ---------------- exact f32 re-rank of flagged rows ----------------
__global__ __launch_bounds__(256) void k_exact(const float* __restrict__ q,
    const float* __restrict__ p, const float* __restrict__ qinv,
    const float* __restrict__ pinv, const unsigned* __restrict__ flags,
    u64* __restrict__ keys) {
  const int row = blockIdx.x;
  if (flags[row] == 0) return;
  const int b = row / N_;
  __shared__ float qs[D_];
  __shared__ u64 wb[4];
  const int t = threadIdx.x;
  const float qn = qinv[row];
  for (int i = t; i < D_; i += 256) qs[i] = q[(size_t)row * D_ + i] * qn;
  __syncthreads();
  const int w = t >> 6, lane = t & 63;
  u64 best = 0;
  for (int i = 0; i < 450; ++i) {
    int m = w + 4 * i;
    const float* pr = p + ((size_t)b * M_ + m) * D_;
    float s = 0.f;
#pragma unroll
    for (int e = 0; e < 12; ++e)
      s = fmaf(qs[lane * 12 + e], pr[lane * 12 + e], s);
    for (int o = 32; o; o >>= 1) s += __shfl_xor(s, o);
    s *= pinv[b * M_ + m];
    u64 k = enc_key(s, m);
    if (k > best) best = k;
  }
  if (lane == 0) wb[w] = best;
  __syncthreads();
  if (t == 0) {
    u64 bb = wb[0];
    for (int i = 1; i < 4; ++i)
      if (wb[i] > bb) bb = wb[i];
    keys[row] = bb;
  }
}

__global__ void k_decode(const u64* __restrict__ keys, float* __restrict__ residual,
                         int* __restrict__ idxbuf, float* __restrict__ out_res,
                         float* __restrict__ out_idx) {
  int i = blockIdx.x * 256 + threadIdx.x;
  if (i >= B_ * N_) return;
  u64 k = keys[i];
  float v = dec_key(k);
  int idx = (int)(0x7FFFFFFFu - (unsigned)(k & 0xFFFFFFFFu));
  if (idx < 0) idx = 0;
  if (idx >= M_) idx = M_ - 1;
  float r = 1.0f - v;
  if (r != r) r = 0.f;
  residual[i] = r;
  idxbuf[i] = idx;
  out_res[i] = r;
  out_idx[i] = (float)idx;
}

// ---------------- ctx -> BN -> cmap (bf16 scratch, [B*N][D]) ----------------
__global__ __launch_bounds__(256) void k_cmap(const float* __restrict__ q,
    const float* __restrict__ p, const int* __restrict__ idxbuf,
    const float* __restrict__ g, const float* __restrict__ bb,
    const float* __restrict__ bm, const float* __restrict__ bv,
    bf16* __restrict__ cmap) {
  int bn = blockIdx.x;
  int b = bn / N_;
  int id = idxbuf[bn];
  if (id < 0) id = 0;
  if (id >= M_) id = M_ - 1;
  const float* qr = q + (size_t)bn * D_;
  const float* pr = p + ((size_t)b * M_ + id) * D_;
  for (int d = threadIdx.x; d < D_; d += 256) {
    float qv = qr[d], pv = pr[d];
    float c = qv + fabsf(qv - pv);
    float val = (c - bm[d]) * (g[d] * rsqrtf(bv[d] + EPS_)) + bb[d];
    cmap[(size_t)bn * D_ + d] = __float2bfloat16(val);
  }
}

// ---------------- weight reshapes to bf16 [cout][k] ----------------
__global__ void k_prepw(const float* __restrict__ lc1, const float* __restrict__ lt1,
                        const float* __restrict__ lc2, const float* __restrict__ lt2,
                        bf16* __restrict__ wt1, bf16* __restrict__ wtT1,
                        bf16* __restrict__ wt2, bf16* __restrict__ wtT2) {
  int i = blockIdx.x * 256 + threadIdx.x;
  const int n1 = 9 * D_ * H_;
  const int n2 = 4 * H_ * H_;
  const int n3 = 9 * H_ * MID_;
  const int n4 = 4 * MID_ * MID_;
  if (i < n1) {
    int co = i / 6912;
    int rem = i % 6912;
    int tap = rem / 768;
    int d = rem % 768;
    wt1[i] = __float2bfloat16(lc1[((size_t)co * D_ + d) * 9 + tap]);
  } else if (i < n1 + n2) {
    int j = i - n1;
    int ij = j >> 16;
    int co = (j >> 8) & 255;
    int ci = j & 255;
    wtT1[j] = __float2bfloat16(lt1[((size_t)ci * H_ + co) * 4 + ij]);
  } else if (i < n1 + n2 + n3) {
    int j = i - n1 - n2;
    int co = j / 2304;
    int rem = j % 2304;
    int tap = rem >> 8;
    int ci = rem & 255;
    wt2[j] = __float2bfloat16(lc2[((size_t)co * H_ + ci) * 9 + tap]);
  } else if (i < n1 + n2 + n3 + n4) {
    int j = i - n1 - n2 - n3;
    int ij = j >> 14;
    int co = (j >> 7) & 127;
    int ci = j & 127;
    wtT2[j] = __float2bfloat16(lt2[((size_t)ci * MID_ + co) * 4 + ij]);
  }
}

// ================= MFMA conv kernels (verified round-7) =================
template <int SHW, int CIN, int COUT>
__global__ __launch_bounds__(256) void k_conv3x3_mfma(
    const bf16* __restrict__ in, const bf16* __restrict__ wt,
    const float* __restrict__ bg, const float* __restrict__ bbeta,
    const float* __restrict__ bm, const float* __restrict__ bv,
    bf16* __restrict__ outp) {
  constexpr int S = SHW * SHW;
  constexpr int K = 9 * CIN;
  constexpr int NS = K / 32;
  constexpr int CS = CIN / 32;
  const int b = blockIdx.z;
  const int s0 = blockIdx.x * 64;
  const int c0 = blockIdx.y * 64;
  __shared__ __align__(16) short As[2][64][40];
  __shared__ __align__(16) short Bs[2][64][40];
  const int t = threadIdx.x;
  const int lane = t & 63;
  const int wm = (t >> 7) & 1;
  const int wn = (t >> 6) & 1;
  const int srow = t >> 2;
  const int sch = (t & 3) * 8;
  const int s_sp = s0 + srow;
  const int sy0 = s_sp / SHW, sx0 = s_sp % SHW;
  const bf16* inb = in + (size_t)b * S * CIN;
  const bf16* wrow = wt + (size_t)(c0 + srow) * K;
  const int lr = lane & 15;
  const int lk = (lane >> 4) * 8;

  f32x4 acc00 = {0.f, 0.f, 0.f, 0.f}, acc01 = {0.f, 0.f, 0.f, 0.f};
  f32x4 acc10 = {0.f, 0.f, 0.f, 0.f}, acc11 = {0.f, 0.f, 0.f, 0.f};

  auto loadA = [&](int kt) -> bf16x8 {
    int tap = kt / CS;
    int c00 = (kt % CS) * 32;
    int dy = tap / 3 - 1, dx = tap % 3 - 1;
    int sy = sy0 + dy, sx = sx0 + dx;
    bf16x8 av = {0, 0, 0, 0, 0, 0, 0, 0};
    if (s_sp < S && sy >= 0 && sy < SHW && sx >= 0 && sx < SHW)
      av = *(const bf16x8*)(inb + (size_t)(sy * SHW + sx) * CIN + c00 + sch);
    return av;
  };

  {
    bf16x8 av = loadA(0);
    bf16x8 wv = *(const bf16x8*)(wrow + sch);
    *(bf16x8*)&As[0][srow][sch] = av;
    *(bf16x8*)&Bs[0][srow][sch] = wv;
  }
  __syncthreads();
  int cur = 0;
  for (int kt = 0; kt < NS; ++kt) {
    bf16x8 avn, wvn;
    if (kt + 1 < NS) {
      avn = loadA(kt + 1);
      wvn = *(const bf16x8*)(wrow + (kt + 1) * 32 + sch);
    }
    bf16x8 a0 = *(const bf16x8*)&As[cur][wm * 32 + lr][lk];
    bf16x8 a1 = *(const bf16x8*)&As[cur][wm * 32 + 16 + lr][lk];
    bf16x8 b0 = *(const bf16x8*)&Bs[cur][wn * 32 + lr][lk];
    bf16x8 b1 = *(const bf16x8*)&Bs[cur][wn * 32 + 16 + lr][lk];
    acc00 = __builtin_amdgcn_mfma_f32_16x16x32_bf16(a0, b0, acc00, 0, 0, 0);
    acc01 = __builtin_amdgcn_mfma_f32_16x16x32_bf16(a0, b1, acc01, 0, 0, 0);
    acc10 = __builtin_amdgcn_mfma_f32_16x16x32_bf16(a1, b0, acc10, 0, 0, 0);
    acc11 = __builtin_amdgcn_mfma_f32_16x16x32_bf16(a1, b1, acc11, 0, 0, 0);
    if (kt + 1 < NS) {
      *(bf16x8*)&As[cur ^ 1][srow][sch] = avn;
      *(bf16x8*)&Bs[cur ^ 1][srow][sch] = wvn;
    }
    __syncthreads();
    cur ^= 1;
  }

  auto emit = [&](const f32x4& a, int mi, int ni) {
    int c = c0 + wn * 32 + ni * 16 + lr;
    float sg = bg[c] * rsqrtf(bv[c] + EPS_);
    float sh = bbeta[c] - bm[c] * sg;
#pragma unroll
    for (int r = 0; r < 4; ++r) {
      int s = s0 + wm * 32 + mi * 16 + (lane >> 4) * 4 + r;
      if (s < S)
        outp[((size_t)b * S + s) * COUT + c] =
            __float2bfloat16(fmaxf(fmaf(a[r], sg, sh), 0.f));
    }
  };
  emit(acc00, 0, 0);
  emit(acc01, 0, 1);
  emit(acc10, 1, 0);
  emit(acc11, 1, 1);
}

template <int SHW, int C>
__global__ __launch_bounds__(256) void k_convT_mfma(
    const bf16* __restrict__ in, const bf16* __restrict__ wt,
    const float* __restrict__ bias, bf16* __restrict__ outp) {
  constexpr int S = SHW * SHW;
  constexpr int NS = C / 32;
  const int b = blockIdx.z;
  const int ij = blockIdx.y & 3;
  const int c0 = (blockIdx.y >> 2) * 64;
  const int s0 = blockIdx.x * 64;
  __shared__ __align__(16) short As[2][64][40];
  __shared__ __align__(16) short Bs[2][64][40];
  const int t = threadIdx.x;
  const int lane = t & 63;
  const int wm = (t >> 7) & 1;
  const int wn = (t >> 6) & 1;
  const int srow = t >> 2;
  const int sch = (t & 3) * 8;
  const int s_sp = s0 + srow;
  const bf16* arow = in + ((size_t)b * S + s_sp) * C;
  const bf16* wrow = wt + (size_t)ij * C * C + (size_t)(c0 + srow) * C;
  const int lr = lane & 15;
  const int lk = (lane >> 4) * 8;

  f32x4 acc00 = {0.f, 0.f, 0.f, 0.f}, acc01 = {0.f, 0.f, 0.f, 0.f};
  f32x4 acc10 = {0.f, 0.f, 0.f, 0.f}, acc11 = {0.f, 0.f, 0.f, 0.f};

  {
    bf16x8 av = {0, 0, 0, 0, 0, 0, 0, 0};
    if (s_sp < S) av = *(const bf16x8*)(arow + sch);
    bf16x8 wv = *(const bf16x8*)(wrow + sch);
    *(bf16x8*)&As[0][srow][sch] = av;
    *(bf16x8*)&Bs[0][srow][sch] = wv;
  }
  __syncthreads();
  int cur = 0;
  for (int kt = 0; kt < NS; ++kt) {
    bf16x8 avn = {0, 0, 0, 0, 0, 0, 0, 0}, wvn;
    if (kt + 1 < NS) {
      if (s_sp < S) avn = *(const bf16x8*)(arow + (kt + 1) * 32 + sch);
      wvn = *(const bf16x8*)(wrow + (kt + 1) * 32 + sch);
    }
    bf16x8 a0 = *(const bf16x8*)&As[cur][wm * 32 + lr][lk];
    bf16x8 a1 = *(const bf16x8*)&As[cur][wm * 32 + 16 + lr][lk];
    bf16x8 b0 = *(const bf16x8*)&Bs[cur][wn * 32 + lr][lk];
    bf16x8 b1 = *(const bf16x8*)&Bs[cur][wn * 32 + 16 + lr][lk];
    acc00 = __builtin_amdgcn_mfma_f32_16x16x32_bf16(a0, b0, acc00, 0, 0, 0);
    acc01 = __builtin_amdgcn_mfma_f32_16x16x32_bf16(a0, b1, acc01, 0, 0, 0);
    acc10 = __builtin_amdgcn_mfma_f32_16x16x32_bf16(a1, b0, acc10, 0, 0, 0);
    acc11 = __builtin_amdgcn_mfma_f32_16x16x32_bf16(a1, b1, acc11, 0, 0, 0);
    if (kt + 1 < NS) {
      *(bf16x8*)&As[cur ^ 1][srow][sch] = avn;
      *(bf16x8*)&Bs[cur ^ 1][srow][sch] = wvn;
    }
    __syncthreads();
    cur ^= 1;
  }

  auto emit = [&](const f32x4& a, int mi, int ni) {
    int c = c0 + wn * 32 + ni * 16 + lr;
    float bj = bias[c];
#pragma unroll
    for (int r = 0; r < 4; ++r) {
      int s = s0 + wm * 32 + mi * 16 + (lane >> 4) * 4 + r;
      if (s < S) {
        int oy = 2 * (s / SHW) + (ij >> 1);
        int ox = 2 * (s % SHW) + (ij & 1);
        outp[((size_t)b * 4 * S + (size_t)oy * (2 * SHW) + ox) * C + c] =
            __float2bfloat16(a[r] + bj);
      }
    }
  };
  emit(acc00, 0, 0);
  emit(acc01, 0, 1);
  emit(acc10, 1, 0);
  emit(acc11, 1, 1);
}

__global__ __launch_bounds__(256) void k_convT_fuse_mfma(
    const bf16* __restrict__ in, const bf16* __restrict__ wt,
    const float* __restrict__ w3, float* __restrict__ l2c) {
  constexpr int SHW = 30, C = 128, S = SHW * SHW;
  constexpr int NS = C / 32;
  const int b = blockIdx.z;
  const int ij = blockIdx.y & 3;
  const int c0 = (blockIdx.y >> 2) * 64;
  const int s0 = blockIdx.x * 64;
  __shared__ __align__(16) short As[2][64][40];
  __shared__ __align__(16) short Bs[2][64][40];
  __shared__ float red0[64][2];
  __shared__ float red1[64][2];
  const int t = threadIdx.x;
  const int lane = t & 63;
  const int wm = (t >> 7) & 1;
  const int wn = (t >> 6) & 1;
  const int srow = t >> 2;
  const int sch = (t & 3) * 8;
  const int s_sp = s0 + srow;
  const bf16* arow = in + ((size_t)b * S + s_sp) * C;
  const bf16* wrow = wt + (size_t)ij * C * C + (size_t)(c0 + srow) * C;
  const int lr = lane & 15;
  const int lk = (lane >> 4) * 8;

  f32x4 acc00 = {0.f, 0.f, 0.f, 0.f}, acc01 = {0.f, 0.f, 0.f, 0.f};
  f32x4 acc10 = {0.f, 0.f, 0.f, 0.f}, acc11 = {0.f, 0.f, 0.f, 0.f};

  {
    bf16x8 av = {0, 0, 0, 0, 0, 0, 0, 0};
    if (s_sp < S) av = *(const bf16x8*)(arow + sch);
    bf16x8 wv = *(const bf16x8*)(wrow + sch);
    *(bf16x8*)&As[0][srow][sch] = av;
    *(bf16x8*)&Bs[0][srow][sch] = wv;
  }
  __syncthreads();
  int cur = 0;
  for (int kt = 0; kt < NS; ++kt) {
    bf16x8 avn = {0, 0, 0, 0, 0, 0, 0, 0}, wvn;
    if (kt + 1 < NS) {
      if (s_sp < S) avn = *(const bf16x8*)(arow + (kt + 1) * 32 + sch);
      wvn = *(const bf16x8*)(wrow + (kt + 1) * 32 + sch);
    }
    bf16x8 a0 = *(const bf16x8*)&As[cur][wm * 32 + lr][lk];
    bf16x8 a1 = *(const bf16x8*)&As[cur][wm * 32 + 16 + lr][lk];
    bf16x8 b0 = *(const bf16x8*)&Bs[cur][wn * 32 + lr][lk];
    bf16x8 b1 = *(const bf16x8*)&Bs[cur][wn * 32 + 16 + lr][lk];
    acc00 = __builtin_amdgcn_mfma_f32_16x16x32_bf16(a0, b0, acc00, 0, 0, 0);
    acc01 = __builtin_amdgcn_mfma_f32_16x16x32_bf16(a0, b1, acc01, 0, 0, 0);
    acc10 = __builtin_amdgcn_mfma_f32_16x16x32_bf16(a1, b0, acc10, 0, 0, 0);
    acc11 = __builtin_amdgcn_mfma_f32_16x16x32_bf16(a1, b1, acc11, 0, 0, 0);
    if (kt + 1 < NS) {
      *(bf16x8*)&As[cur ^ 1][srow][sch] = avn;
      *(bf16x8*)&Bs[cur ^ 1][srow][sch] = wvn;
    }
    __syncthreads();
    cur ^= 1;
  }

  const float w0a = w3[c0 + wn * 32 + lr];
  const float w0b = w3[c0 + wn * 32 + 16 + lr];
  const float w1a = w3[MID_ + c0 + wn * 32 + lr];
  const float w1b = w3[MID_ + c0 + wn * 32 + 16 + lr];
#pragma unroll
  for (int mi = 0; mi < 2; ++mi) {
    f32x4 aa0 = mi ? acc10 : acc00;
    f32x4 aa1 = mi ? acc11 : acc01;
#pragma unroll
    for (int r = 0; r < 4; ++r) {
      float p0 = aa0[r] * w0a + aa1[r] * w0b;
      float p1 = aa0[r] * w1a + aa1[r] * w1b;
      p0 += __shfl_xor(p0, 1); p0 += __shfl_xor(p0, 2);
      p0 += __shfl_xor(p0, 4); p0 += __shfl_xor(p0, 8);
      p1 += __shfl_xor(p1, 1); p1 += __shfl_xor(p1, 2);
      p1 += __shfl_xor(p1, 4); p1 += __shfl_xor(p1, 8);
      if (lr == 0) {
        int rl = wm * 32 + mi * 16 + (lane >> 4) * 4 + r;
        red0[rl][wn] = p0;
        red1[rl][wn] = p1;
      }
    }
  }
  __syncthreads();
  if (t < 64) {
    int s = s0 + t;
    if (s < S) {
      float v0 = red0[t][0] + red0[t][1];
      float v1 = red1[t][0] + red1[t][1];
      int oy = 2 * (s / SHW) + (ij >> 1);
      int ox = 2 * (s % SHW) + (ij & 1);
      int opix = oy * 60 + ox;
      atomicAdd(&l2c[(size_t)b * 7200 + opix], v0);
      atomicAdd(&l2c[(size_t)b * 7200 + 3600 + opix], v1);
    }
  }
}

// ---------------- l2c init ----------------
__global__ void k_l2cinit(const float* __restrict__ lt2b, const float* __restrict__ w3,
                          const float* __restrict__ b3, float* __restrict__ l2c) {
  __shared__ float ini[2];
  int t = threadIdx.x;
  if (t < 2) {
    float s = b3[t];
    for (int ci = 0; ci < MID_; ++ci) s = fmaf(lt2b[ci], w3[t * MID_ + ci], s);
    ini[t] = s;
  }
  __syncthreads();
  int i = blockIdx.x * 256 + t;
  if (i < 7200) l2c[(size_t)blockIdx.y * 7200 + i] = ini[i / 3600];
}

// ---------------- patch head ----------------
__global__ __launch_bounds__(256) void k_patch(const float* __restrict__ l2c,
    const float* __restrict__ residual, float* __restrict__ out_ev,
    float* __restrict__ out_pl) {
  const int b = blockIdx.x;
  __shared__ float sm0[3600];
  __shared__ float sm1[3600];
  for (int i = threadIdx.x; i < 3600; i += 256) {
    sm0[i] = l2c[(size_t)b * 7200 + i];
    sm1[i] = l2c[(size_t)b * 7200 + 3600 + i];
  }
  __syncthreads();
  const int t = threadIdx.x;
  if (t >= 225) return;
  const int py = t / 15, px = t % 15;
  const float cy = 16.f * py + 7.5f;
  const float cx = 16.f * px + 7.5f;
  const int ky_lo = max(0, 16 * py - 8), ky_hi = min(239, 16 * py + 23);
  const int kx_lo = max(0, 16 * px - 8), kx_hi = min(239, 16 * px + 23);
  float acc0 = 0.f, acc1 = 0.f, wsum = 0.f;
  for (int ky = ky_lo; ky <= ky_hi; ++ky) {
    float wy = 1.f - fabsf((float)ky - cy) * 0.0625f;
    float c60y = 0.25f * ky - 0.375f;
    int jy = (int)floorf(c60y);
    float fy = c60y - (float)jy;
    int jy0 = max(jy, 0), jy1 = min(jy + 1, 59);
    for (int kx = kx_lo; kx <= kx_hi; ++kx) {
      float wx = 1.f - fabsf((float)kx - cx) * 0.0625f;
      float w = wy * wx;
      float c60x = 0.25f * kx - 0.375f;
      int jx = (int)floorf(c60x);
      float fx = c60x - (float)jx;
      int jx0 = max(jx, 0), jx1 = min(jx + 1, 59);
      float v0 = (1.f - fy) * ((1.f - fx) * sm0[jy0 * 60 + jx0] + fx * sm0[jy0 * 60 + jx1])
               + fy * ((1.f - fx) * sm0[jy1 * 60 + jx0] + fx * sm0[jy1 * 60 + jx1]);
      float v1 = (1.f - fy) * ((1.f - fx) * sm1[jy0 * 60 + jx0] + fx * sm1[jy0 * 60 + jx1])
               + fy * ((1.f - fx) * sm1[jy1 * 60 + jx0] + fx * sm1[jy1 * 60 + jx1]);
      acc0 = fmaf(w, v0, acc0);
      acc1 = fmaf(w, v1, acc1);
      wsum += w;
    }
  }
  float p0 = acc0 / wsum, p1 = acc1 / wsum;
  float logit = p1 - p0;
  float score1 = 1.0f / (1.0f + expf(p0 - p1));
  float ev = 0.5f * residual[b * N_ + t] + 0.5f * score1;
  out_pl[b * N_ + t] = logit;
  out_ev[b * N_ + t] = ev;
}

// ---------------- upsample 60->240 bilinear ----------------
__global__ __launch_bounds__(256) void k_up(const float* __restrict__ l2c,
                                            float* __restrict__ out_l2c,
                                            float* __restrict__ out_ls) {
  const int b = blockIdx.y;
  const int pix = blockIdx.x * 256 + threadIdx.x;
  const int y = pix / 240, x = pix % 240;
  float sy = 0.25f * y - 0.375f;
  int ky = (int)floorf(sy);
  float fy = sy - (float)ky;
  float sx = 0.25f * x - 0.375f;
  int kx = (int)floorf(sx);
  float fx = sx - (float)kx;
  int ky0 = max(ky, 0), ky1 = min(ky + 1, 59);
  int kx0 = max(kx, 0), kx1 = min(kx + 1, 59);
  float v[2];
#pragma unroll
  for (int c = 0; c < 2; ++c) {
    const float* base = l2c + ((size_t)b * 2 + c) * 3600;
    float top = (1.f - fx) * base[ky0 * 60 + kx0] + fx * base[ky0 * 60 + kx1];
    float bot = (1.f - fx) * base[ky1 * 60 + kx0] + fx * base[ky1 * 60 + kx1];
    v[c] = (1.f - fy) * top + fy * bot;
  }
  float s1 = 1.f / (1.f + expf(v[0] - v[1]));
  float s0 = 1.f / (1.f + expf(v[1] - v[0]));
  size_t o0 = ((size_t)b * 2 + 0) * 57600 + pix;
  size_t o1 = ((size_t)b * 2 + 1) * 57600 + pix;
  out_l2c[o0] = v[0];
  out_l2c[o1] = v[1];
  out_ls[o0] = s0;
  out_ls[o1] = s1;
}

// ---------------- fusion stats ----------------
__global__ __launch_bounds__(256) void k_fusion(const bf16* __restrict__ cmap,
                                                float* __restrict__ gfeat) {
  int wid = ((blockIdx.x * 256 + threadIdx.x) >> 6);
  int lane = threadIdx.x & 63;
  if (wid >= B_ * D_) return;
  int b = wid / D_, d = wid % D_;
  const bf16* base = cmap + (size_t)b * N_ * D_ + d;
  float v[4];
  bool alive[4];
  float sum = 0.f;
#pragma unroll
  for (int r = 0; r < 4; ++r) {
    int n = lane + r * 64;
    bool ok = (n < N_);
    v[r] = ok ? __bfloat162float(base[(size_t)n * D_]) : -INFINITY;
    alive[r] = ok;
    if (ok) sum += v[r];
  }
  for (int o = 32; o > 0; o >>= 1) sum += __shfl_xor(sum, o);
  float topsum = 0.f;
  for (int it = 0; it < 10; ++it) {
    float lm = -INFINITY;
    int ls = -1;
#pragma unroll
    for (int r = 0; r < 4; ++r)
      if (alive[r] && v[r] > lm) { lm = v[r]; ls = r; }
    float wm = lm;
    for (int o = 32; o > 0; o >>= 1) wm = fmaxf(wm, __shfl_xor(wm, o));
    topsum += wm;
    u64 ball = __ballot(lm == wm);
    int owner = __ffsll((long long)ball) - 1;
    if (lane == owner && ls >= 0) alive[ls] = false;
  }
  if (lane == 0) gfeat[wid] = 0.5f * (sum / 225.0f + topsum * 0.1f);
}

// ---------------- fused FC head ----------------
__global__ __launch_bounds__(256) void k_fc(const float* __restrict__ gfeat,
    const float* __restrict__ g1w, const float* __restrict__ bg1,
    const float* __restrict__ bb1, const float* __restrict__ bm1,
    const float* __restrict__ bv1, const float* __restrict__ g2w,
    const float* __restrict__ bg2, const float* __restrict__ bb2,
    const float* __restrict__ bm2, const float* __restrict__ bv2,
    const float* __restrict__ g3w, float* __restrict__ out_gl,
    float* __restrict__ out_g2c) {
  __shared__ float gf[D_];
  __shared__ float h1s[H_];
  __shared__ float h2s[MID_];
  __shared__ float g2cs[2];
  const int b = blockIdx.x;
  const int t = threadIdx.x;
  for (int i = t; i < D_; i += 256) gf[i] = gfeat[b * D_ + i];
  __syncthreads();
  {
    float a = 0.f;
    const float* w = g1w + (size_t)t * D_;
    for (int d = 0; d < D_; ++d) a = fmaf(gf[d], w[d], a);
    float s = bg1[t] * rsqrtf(bv1[t] + EPS_);
    h1s[t] = fmaxf((a - bm1[t]) * s + bb1[t], 0.f);
  }
  __syncthreads();
  if (t < MID_) {
    float a = 0.f;
    const float* w = g2w + (size_t)t * H_;
    for (int k = 0; k < H_; ++k) a = fmaf(h1s[k], w[k], a);
    float s = bg2[t] * rsqrtf(bv2[t] + EPS_);
    h2s[t] = fmaxf((a - bm2[t]) * s + bb2[t], 0.f);
  }
  __syncthreads();
  if (t < 2) {
    float a = 0.f;
    const float* w = g3w + (size_t)t * MID_;
    for (int k = 0; k < MID_; ++k) a = fmaf(h2s[k], w[k], a);
    g2cs[t] = a;
    out_g2c[b * 2 + t] = a;
  }
  __syncthreads();
  if (t == 0) out_gl[b] = g2cs[1] - g2cs[0];
}

// ================= host =================
extern "C" void kernel_launch(void* const* d_in, const int* in_sizes, int n_in,
                              void* d_out, int out_size, void* d_ws, size_t ws_size,
                              hipStream_t stream) {
  (void)in_sizes; (void)n_in; (void)out_size; (void)ws_size;
  const float* query = (const float*)d_in[0];
  const float* prompt = (const float*)d_in[1];
  const float* bns_g = (const float*)d_in[2];
  const float* bns_b = (const float*)d_in[3];
  const float* bns_m = (const float*)d_in[4];
  const float* bns_v = (const float*)d_in[5];
  const float* lc1_w = (const float*)d_in[6];
  const float* lbn1_g = (const float*)d_in[7];
  const float* lbn1_b = (const float*)d_in[8];
  const float* lbn1_m = (const float*)d_in[9];
  const float* lbn1_v = (const float*)d_in[10];
  const float* lt1_w = (const float*)d_in[11];
  const float* lt1_b = (const float*)d_in[12];
  const float* lc2_w = (const float*)d_in[13];
  const float* lbn2_g = (const float*)d_in[14];
  const float* lbn2_b = (const float*)d_in[15];
  const float* lbn2_m = (const float*)d_in[16];
  const float* lbn2_v = (const float*)d_in[17];
  const float* lt2_w = (const float*)d_in[18];
  const float* lt2_b = (const float*)d_in[19];
  const float* lc3_w = (const float*)d_in[20];
  const float* lc3_b = (const float*)d_in[21];
  const float* g1_w = (const float*)d_in[22];
  const float* gbn1_g = (const float*)d_in[23];
  const float* gbn1_b = (const float*)d_in[24];
  const float* gbn1_m = (const float*)d_in[25];
  const float* gbn1_v = (const float*)d_in[26];
  const float* g2_w = (const float*)d_in[27];
  const float* gbn2_g = (const float*)d_in[28];
  const float* gbn2_b = (const float*)d_in[29];
  const float* gbn2_m = (const float*)d_in[30];
  const float* gbn2_v = (const float*)d_in[31];
  const float* g3_w = (const float*)d_in[32];

  float* ob = (float*)d_out;  // output is float32
  char* ob_c = (char*)d_out;
  char* ws = (char*)d_ws;
  // --- workspace (~8.5 MB) ---
  u64* keys = (u64*)(ws + 0);                    // 57,600 B
  float* qinv = (float*)(ws + 57600);            // 28,800
  float* pinv = (float*)(ws + 86400);            // 230,400
  float* residual = (float*)(ws + 316800);       // 57,600
  int* idxbuf = (int*)(ws + 374400);             // 28,800
  float* gfeat = (float*)(ws + 403200);          // 98,304
  float* l2c = (float*)(ws + 501504);            // 1,843,200
  bf16* wt1 = (bf16*)(ws + 2344704);             // 3,538,944
  bf16* wtT1 = (bf16*)(ws + 5883648);            // 524,288
  bf16* wt2 = (bf16*)(ws + 6407936);             // 589,824
  bf16* wtT2 = (bf16*)(ws + 6997760);            // 131,072
  unsigned* flags = (unsigned*)(ws + 7128832);   // 28,800
  u64* pkeys = (u64*)(ws + 7157632);             // 864,000
  float* pmax2 = (float*)(ws + 8021632);         // 432,000 -> end 8,453,632

  // output offsets in f32 elements (return order: ev, pl, gl, g2c, l2c, ls, res, idx)
  const size_t OFF_EV = 0;
  const size_t OFF_PL = 14400;
  const size_t OFF_GL = 28800;
  const size_t OFF_G2C = 28864;
  const size_t OFF_L2C = 28992;
  const size_t OFF_LS = 7401792;
  const size_t OFF_RES = 14774592;
  const size_t OFF_IDX = 14788992;

  // bf16 conv scratch packed into the BYTE range of the l2c/ls chunks
  bf16* cmap = (bf16*)(ob_c + 115968);
  bf16* x1 = (bf16*)(ob_c + 11175168);
  bf16* y1 = (bf16*)(ob_c + 14861568);
  bf16* x2 = (bf16*)(ob_c + 29607168);

  // ---------- phase A ----------
  for (int l = 0; l < L_; ++l) {
    const float* q = query + (size_t)l * B_ * N_ * D_;
    const float* p = prompt + (size_t)l * B_ * M_ * D_;
    float* out_gl = ob + OFF_GL + (size_t)l * B_;
    float* out_g2c = ob + OFF_G2C + (size_t)l * B_ * 2;
    float* out_res = ob + OFF_RES + (size_t)l * B_ * N_;
    float* out_idx = ob + OFF_IDX + (size_t)l * B_ * N_;
    float* res_l = residual + (size_t)l * B_ * N_;
    float* l2c_l = l2c + (size_t)l * B_ * 7200;

    k_norms<<<dim3(B_ * (N_ + M_)), dim3(256), 0, stream>>>(q, p, qinv, pinv);
    k_sim3<<<dim3(15, B_), dim3(256), 0, stream>>>(q, p, qinv, pinv, pkeys, pmax2);
    k_reduce<<<dim3(29), dim3(256), 0, stream>>>(pkeys, pmax2, keys, flags);
    k_exact<<<dim3(B_ * N_), dim3(256), 0, stream>>>(q, p, qinv, pinv, flags, keys);
    k_decode<<<dim3(29), dim3(256), 0, stream>>>(keys, res_l, idxbuf, out_res, out_idx);
    k_cmap<<<dim3(B_ * N_), dim3(256), 0, stream>>>(q, p, idxbuf,
        bns_g + l * D_, bns_b + l * D_, bns_m + l * D_, bns_v + l * D_, cmap);
    k_fusion<<<dim3(B_ * D_ / 4), dim3(256), 0, stream>>>(cmap, gfeat);
    k_fc<<<dim3(B_), dim3(256), 0, stream>>>(gfeat,
        g1_w + (size_t)l * H_ * D_, gbn1_g + l * H_, gbn1_b + l * H_, gbn1_m + l * H_, gbn1_v + l * H_,
        g2_w + (size_t)l * MID_ * H_, gbn2_g + l * MID_, gbn2_b + l * MID_, gbn2_m + l * MID_, gbn2_v + l * MID_,
        g3_w + (size_t)l * 2 * MID_, out_gl, out_g2c);
    k_prepw<<<dim3(9344), dim3(256), 0, stream>>>(
        lc1_w + (size_t)l * H_ * D_ * 9, lt1_w + (size_t)l * H_ * H_ * 4,
        lc2_w + (size_t)l * MID_ * H_ * 9, lt2_w + (size_t)l * MID_ * MID_ * 4,
        wt1, wtT1, wt2, wtT2);
    k_l2cinit<<<dim3(29, B_), dim3(256), 0, stream>>>(lt2_b + l * MID_,
        lc3_w + (size_t)l * 2 * MID_, lc3_b + l * 2, l2c_l);
    k_conv3x3_mfma<15, 768, 256><<<dim3(4, 4, B_), dim3(256), 0, stream>>>(cmap, wt1,
        lbn1_g + l * H_, lbn1_b + l * H_, lbn1_m + l * H_, lbn1_v + l * H_, x1);
    k_convT_mfma<15, 256><<<dim3(4, 16, B_), dim3(256), 0, stream>>>(x1, wtT1,
        lt1_b + l * H_, y1);
    k_conv3x3_mfma<30, 256, 128><<<dim3(15, 2, B_), dim3(256), 0, stream>>>(y1, wt2,
        lbn2_g + l * MID_, lbn2_b + l * MID_, lbn2_m + l * MID_, lbn2_v + l * MID_, x2);
    k_convT_fuse_mfma<<<dim3(15, 8, B_), dim3(256), 0, stream>>>(x2, wtT2,
        lc3_w + (size_t)l * 2 * MID_, l2c_l);
  }

  // ---------- phase B ----------
  for (int l = 0; l < L_; ++l) {
    float* out_ev = ob + OFF_EV + (size_t)l * B_ * N_;
    float* out_pl = ob + OFF_PL + (size_t)l * B_ * N_;
    float* out_l2c = ob + OFF_L2C + (size_t)l * B_ * 2 * 57600;
    float* out_ls = ob + OFF_LS + (size_t)l * B_ * 2 * 57600;
    float* res_l = residual + (size_t)l * B_ * N_;
    float* l2c_l = l2c + (size_t)l * B_ * 7200;
    k_patch<<<dim3(B_), dim3(256), 0, stream>>>(l2c_l, res_l, out_ev, out_pl);
    k_up<<<dim3(225, B_), dim3(256), 0, stream>>>(l2c_l, out_l2c, out_ls);
  }
}

// Round 11
// 1388.953 us; speedup vs baseline: 1.9763x; 1.2794x over previous
//
#include <hip/hip_runtime.h>
#include <hip/hip_bf16.h>
#include <math.h>

typedef unsigned long long u64;
typedef __hip_bfloat16 bf16;
typedef __attribute__((ext_vector_type(8))) short bf16x8;
typedef __attribute__((ext_vector_type(4))) float f32x4;

#define L_ 2
#define B_ 32
#define N_ 225
#define M_ 1800
#define D_ 768
#define H_ 256
#define MID_ 128
#define EPS_ 1e-5f
#define DELTA_ 1e-5f

__device__ __forceinline__ u64 enc_key(float v, int idx) {
  unsigned u = __float_as_uint(v);
  u = (u & 0x80000000u) ? ~u : (u | 0x80000000u);
  return ((u64)u << 32) | (u64)(0x7FFFFFFFu - (unsigned)idx);
}

__device__ __forceinline__ float dec_key(u64 k) {
  unsigned u = (unsigned)(k >> 32);
  unsigned bits = (u & 0x80000000u) ? (u & 0x7FFFFFFFu) : ~u;
  return __uint_as_float(bits);
}

__device__ __forceinline__ short f2bs(float x) {
  __hip_bfloat16 h = __float2bfloat16(x);
  return *reinterpret_cast<short*>(&h);
}

// convert 8 normalized floats to hi/lo bf16 pairs
__device__ __forceinline__ void cvt8(const float4& A, const float4& Bv, float nv,
                                     bf16x8& hi, bf16x8& lo) {
  float x[8] = {A.x * nv, A.y * nv, A.z * nv, A.w * nv,
                Bv.x * nv, Bv.y * nv, Bv.z * nv, Bv.w * nv};
#pragma unroll
  for (int e = 0; e < 8; ++e) {
    short h = f2bs(x[e]);
    float hf = __uint_as_float(((unsigned)(unsigned short)h) << 16);
    hi[e] = h;
    lo[e] = f2bs(x[e] - hf);
  }
}

// ---------------- norms ----------------
__global__ __launch_bounds__(256) void k_norms(const float* __restrict__ q,
                                               const float* __restrict__ p,
                                               float* __restrict__ qinv,
                                               float* __restrict__ pinv) {
  int row = blockIdx.x;
  const float* src;
  float* dst;
  if (row < B_ * N_) {
    src = q + (size_t)row * D_;
    dst = qinv + row;
  } else {
    int r = row - B_ * N_;
    src = p + (size_t)r * D_;
    dst = pinv + r;
  }
  float s = 0.f;
  for (int i = threadIdx.x; i < D_; i += 256) {
    float v = src[i];
    s = fmaf(v, v, s);
  }
  __shared__ float red[256];
  red[threadIdx.x] = s;
  __syncthreads();
  for (int off = 128; off > 0; off >>= 1) {
    if (threadIdx.x < off) red[threadIdx.x] += red[threadIdx.x + off];
    __syncthreads();
  }
  if (threadIdx.x == 0) {
    float n = sqrtf(red[0]);
    n = fmaxf(n, 1e-12f);
    *dst = 1.0f / n;
  }
}

// ---------------- split-bf16 sim: block = (m-tile 128) x (all 240 n) ----------------
__global__ __launch_bounds__(256, 2) void k_sim3(const float* __restrict__ q,
    const float* __restrict__ p, const float* __restrict__ qinv,
    const float* __restrict__ pinv, u64* __restrict__ pkeys,
    float* __restrict__ pmax2) {
  const int mt = blockIdx.x;
  const int b = blockIdx.y;
  const int m0 = mt * 128;
  __shared__ __align__(16) short Ph[128][40];
  __shared__ __align__(16) short Pl[128][40];
  __shared__ __align__(16) short Qh[256][40];
  __shared__ __align__(16) short Ql[256][40];
  const int t = threadIdx.x;
  const int lane = t & 63;
  const int w = t >> 6;
  const int lr = lane & 15;
  const int lg = lane >> 4;
  const float* qb = q + (size_t)b * N_ * D_;
  const float* pb = p + (size_t)b * M_ * D_;

  f32x4 acc[8][4];
#pragma unroll
  for (int mg = 0; mg < 8; ++mg)
#pragma unroll
    for (int ng = 0; ng < 4; ++ng) acc[mg][ng] = (f32x4){0.f, 0.f, 0.f, 0.f};

  for (int kc = 0; kc < 24; ++kc) {
    const int k0 = kc * 32;
    __syncthreads();
    // stage p (128 rows x 32 k): 512 groups of 8
#pragma unroll
    for (int i = 0; i < 2; ++i) {
      int g = t + 256 * i;
      int row = g >> 2, koff = (g & 3) * 8;
      int m = m0 + row;
      float4 A = {0, 0, 0, 0}, Bv = {0, 0, 0, 0};
      float nv = 0.f;
      if (m < M_) {
        nv = pinv[b * M_ + m];
        const float* src = pb + (size_t)m * D_ + k0 + koff;
        A = *(const float4*)src;
        Bv = *(const float4*)(src + 4);
      }
      bf16x8 hi, lo;
      cvt8(A, Bv, nv, hi, lo);
      *(bf16x8*)&Ph[row][koff] = hi;
      *(bf16x8*)&Pl[row][koff] = lo;
    }
    // stage q (256 rows x 32 k, rows >=225 zero): 1024 groups of 8
#pragma unroll
    for (int i = 0; i < 4; ++i) {
      int g = t + 256 * i;
      int row = g >> 2, koff = (g & 3) * 8;
      float4 A = {0, 0, 0, 0}, Bv = {0, 0, 0, 0};
      float nv = 0.f;
      if (row < N_) {
        nv = qinv[b * N_ + row];
        const float* src = qb + (size_t)row * D_ + k0 + koff;
        A = *(const float4*)src;
        Bv = *(const float4*)(src + 4);
      }
      bf16x8 hi, lo;
      cvt8(A, Bv, nv, hi, lo);
      *(bf16x8*)&Qh[row][koff] = hi;
      *(bf16x8*)&Ql[row][koff] = lo;
    }
    __syncthreads();
    // MFMA: wave w owns n-frags w*4 .. w*4+3
    bf16x8 qh[4], ql[4];
#pragma unroll
    for (int ng = 0; ng < 4; ++ng) {
      int nrow = (w * 4 + ng) * 16 + lr;
      qh[ng] = *(const bf16x8*)&Qh[nrow][lg * 8];
      ql[ng] = *(const bf16x8*)&Ql[nrow][lg * 8];
    }
#pragma unroll
    for (int mg = 0; mg < 8; ++mg) {
      bf16x8 ph = *(const bf16x8*)&Ph[mg * 16 + lr][lg * 8];
      bf16x8 pl = *(const bf16x8*)&Pl[mg * 16 + lr][lg * 8];
#pragma unroll
      for (int ng = 0; ng < 4; ++ng) {
        acc[mg][ng] = __builtin_amdgcn_mfma_f32_16x16x32_bf16(pl, qh[ng], acc[mg][ng], 0, 0, 0);
        acc[mg][ng] = __builtin_amdgcn_mfma_f32_16x16x32_bf16(ph, ql[ng], acc[mg][ng], 0, 0, 0);
        acc[mg][ng] = __builtin_amdgcn_mfma_f32_16x16x32_bf16(ph, qh[ng], acc[mg][ng], 0, 0, 0);
      }
    }
  }

  // extract per-ng top1/max2 over this block's 128 m-rows
  u64 key1[4];
  float k1v[4], max2[4];
#pragma unroll
  for (int ng = 0; ng < 4; ++ng) { key1[ng] = 0; k1v[ng] = -2.f; max2[ng] = -2.f; }
#pragma unroll
  for (int ng = 0; ng < 4; ++ng) {
#pragma unroll
    for (int mg = 0; mg < 8; ++mg) {
#pragma unroll
      for (int r = 0; r < 4; ++r) {
        int m = m0 + mg * 16 + lg * 4 + r;
        if (m < M_) {
          float v = acc[mg][ng][r];
          u64 k = enc_key(v, m);
          if (k > key1[ng]) {
            max2[ng] = fmaxf(max2[ng], k1v[ng]);
            key1[ng] = k;
            k1v[ng] = v;
          } else if (v > max2[ng]) {
            max2[ng] = v;
          }
        }
      }
    }
  }
  // cross-lg merge (lane^16, lane^32) and write partials
#pragma unroll
  for (int ng = 0; ng < 4; ++ng) {
#pragma unroll
    for (int off = 16; off <= 32; off <<= 1) {
      u64 ok = __shfl_xor(key1[ng], off);
      float okv = __shfl_xor(k1v[ng], off);
      float om2 = __shfl_xor(max2[ng], off);
      if (ok > key1[ng]) {
        max2[ng] = fmaxf(fmaxf(max2[ng], om2), k1v[ng]);
        key1[ng] = ok;
        k1v[ng] = okv;
      } else {
        max2[ng] = fmaxf(fmaxf(max2[ng], om2), okv);
      }
    }
    if (lg == 0) {
      int n = (w * 4 + ng) * 16 + lr;
      if (n < N_) {
        size_t idx = (size_t)mt * (B_ * N_) + b * N_ + n;
        pkeys[idx] = key1[ng];
        pmax2[idx] = max2[ng];
      }
    }
  }
}

// ---------------- merge 15 partials per row -> keys + flag ----------------
// Flagged rows get keys=0 so k_exact's atomicMax rebuilds them exactly.
__global__ void k_reduce(const u64* __restrict__ pkeys, const float* __restrict__ pmax2,
                         u64* __restrict__ keys, unsigned* __restrict__ flags) {
  int row = blockIdx.x * 256 + threadIdx.x;
  if (row >= B_ * N_) return;
  u64 key1 = 0;
  float k1v = -2.f, max2 = -2.f;
  for (int mt = 0; mt < 15; ++mt) {
    u64 k = pkeys[(size_t)mt * (B_ * N_) + row];
    float m2 = pmax2[(size_t)mt * (B_ * N_) + row];
    float kv = dec_key(k);
    if (k > key1) {
      max2 = fmaxf(fmaxf(max2, m2), k1v);
      key1 = k;
      k1v = kv;
    } else {
      max2 = fmaxf(fmaxf(max2, m2), kv);
    }
  }
  unsigned f = (k1v - max2 <= DELTA_) ? 1u : 0u;
  keys[row] = f ? 0ULL : key1;
  flags[row] = f;
}

// ---------------- exact f32 re-rank of flagged rows (m-split x15) ----------------
__global__ __launch_bounds__(256) void k_exact(const float* __restrict__ q,
    const float* __restrict__ p, const float* __restrict__ qinv,
    const float* __restrict__ pinv, const unsigned* __restrict__ flags,
    u64* __restrict__ keys) {
  const int row = blockIdx.x;
  if (flags[row] == 0) return;
  const int m0 = blockIdx.y * 120;
  const int b = row / N_;
  __shared__ float qs[D_];
  __shared__ u64 wb[4];
  const int t = threadIdx.x;
  const float qn = qinv[row];
  for (int i = t; i < D_; i += 256) qs[i] = q[(size_t)row * D_ + i] * qn;
  __syncthreads();
  const int w = t >> 6, lane = t & 63;
  u64 best = 0;
  for (int i = 0; i < 30; ++i) {
    int m = m0 + w + 4 * i;
    const float* pr = p + ((size_t)b * M_ + m) * D_;
    float s = 0.f;
#pragma unroll
    for (int e = 0; e < 12; ++e)
      s = fmaf(qs[lane * 12 + e], pr[lane * 12 + e], s);
    for (int o = 32; o; o >>= 1) s += __shfl_xor(s, o);
    s *= pinv[b * M_ + m];
    u64 k = enc_key(s, m);
    if (k > best) best = k;
  }
  if (lane == 0) wb[w] = best;
  __syncthreads();
  if (t == 0) {
    u64 bb = wb[0];
    for (int i = 1; i < 4; ++i)
      if (wb[i] > bb) bb = wb[i];
    atomicMax(&keys[row], bb);
  }
}

__global__ void k_decode(const u64* __restrict__ keys, float* __restrict__ residual,
                         int* __restrict__ idxbuf, float* __restrict__ out_res,
                         float* __restrict__ out_idx) {
  int i = blockIdx.x * 256 + threadIdx.x;
  if (i >= B_ * N_) return;
  u64 k = keys[i];
  float v = dec_key(k);
  int idx = (int)(0x7FFFFFFFu - (unsigned)(k & 0xFFFFFFFFu));
  if (idx < 0) idx = 0;
  if (idx >= M_) idx = M_ - 1;
  float r = 1.0f - v;
  if (r != r) r = 0.f;
  residual[i] = r;
  idxbuf[i] = idx;
  out_res[i] = r;
  out_idx[i] = (float)idx;
}

// ---------------- ctx -> BN -> cmap (bf16 scratch, [B*N][D]) ----------------
__global__ __launch_bounds__(256) void k_cmap(const float* __restrict__ q,
    const float* __restrict__ p, const int* __restrict__ idxbuf,
    const float* __restrict__ g, const float* __restrict__ bb,
    const float* __restrict__ bm, const float* __restrict__ bv,
    bf16* __restrict__ cmap) {
  int bn = blockIdx.x;
  int b = bn / N_;
  int id = idxbuf[bn];
  if (id < 0) id = 0;
  if (id >= M_) id = M_ - 1;
  const float* qr = q + (size_t)bn * D_;
  const float* pr = p + ((size_t)b * M_ + id) * D_;
  for (int d = threadIdx.x; d < D_; d += 256) {
    float qv = qr[d], pv = pr[d];
    float c = qv + fabsf(qv - pv);
    float val = (c - bm[d]) * (g[d] * rsqrtf(bv[d] + EPS_)) + bb[d];
    cmap[(size_t)bn * D_ + d] = __float2bfloat16(val);
  }
}

// ---------------- weight reshapes to bf16 [cout][k] ----------------
__global__ void k_prepw(const float* __restrict__ lc1, const float* __restrict__ lt1,
                        const float* __restrict__ lc2, const float* __restrict__ lt2,
                        bf16* __restrict__ wt1, bf16* __restrict__ wtT1,
                        bf16* __restrict__ wt2, bf16* __restrict__ wtT2) {
  int i = blockIdx.x * 256 + threadIdx.x;
  const int n1 = 9 * D_ * H_;
  const int n2 = 4 * H_ * H_;
  const int n3 = 9 * H_ * MID_;
  const int n4 = 4 * MID_ * MID_;
  if (i < n1) {
    int co = i / 6912;
    int rem = i % 6912;
    int tap = rem / 768;
    int d = rem % 768;
    wt1[i] = __float2bfloat16(lc1[((size_t)co * D_ + d) * 9 + tap]);
  } else if (i < n1 + n2) {
    int j = i - n1;
    int ij = j >> 16;
    int co = (j >> 8) & 255;
    int ci = j & 255;
    wtT1[j] = __float2bfloat16(lt1[((size_t)ci * H_ + co) * 4 + ij]);
  } else if (i < n1 + n2 + n3) {
    int j = i - n1 - n2;
    int co = j / 2304;
    int rem = j % 2304;
    int tap = rem >> 8;
    int ci = rem & 255;
    wt2[j] = __float2bfloat16(lc2[((size_t)co * H_ + ci) * 9 + tap]);
  } else if (i < n1 + n2 + n3 + n4) {
    int j = i - n1 - n2 - n3;
    int ij = j >> 14;
    int co = (j >> 7) & 127;
    int ci = j & 127;
    wtT2[j] = __float2bfloat16(lt2[((size_t)ci * MID_ + co) * 4 + ij]);
  }
}

// ================= MFMA conv kernels (verified round-7) =================
template <int SHW, int CIN, int COUT>
__global__ __launch_bounds__(256) void k_conv3x3_mfma(
    const bf16* __restrict__ in, const bf16* __restrict__ wt,
    const float* __restrict__ bg, const float* __restrict__ bbeta,
    const float* __restrict__ bm, const float* __restrict__ bv,
    bf16* __restrict__ outp) {
  constexpr int S = SHW * SHW;
  constexpr int K = 9 * CIN;
  constexpr int NS = K / 32;
  constexpr int CS = CIN / 32;
  const int b = blockIdx.z;
  const int s0 = blockIdx.x * 64;
  const int c0 = blockIdx.y * 64;
  __shared__ __align__(16) short As[2][64][40];
  __shared__ __align__(16) short Bs[2][64][40];
  const int t = threadIdx.x;
  const int lane = t & 63;
  const int wm = (t >> 7) & 1;
  const int wn = (t >> 6) & 1;
  const int srow = t >> 2;
  const int sch = (t & 3) * 8;
  const int s_sp = s0 + srow;
  const int sy0 = s_sp / SHW, sx0 = s_sp % SHW;
  const bf16* inb = in + (size_t)b * S * CIN;
  const bf16* wrow = wt + (size_t)(c0 + srow) * K;
  const int lr = lane & 15;
  const int lk = (lane >> 4) * 8;

  f32x4 acc00 = {0.f, 0.f, 0.f, 0.f}, acc01 = {0.f, 0.f, 0.f, 0.f};
  f32x4 acc10 = {0.f, 0.f, 0.f, 0.f}, acc11 = {0.f, 0.f, 0.f, 0.f};

  auto loadA = [&](int kt) -> bf16x8 {
    int tap = kt / CS;
    int c00 = (kt % CS) * 32;
    int dy = tap / 3 - 1, dx = tap % 3 - 1;
    int sy = sy0 + dy, sx = sx0 + dx;
    bf16x8 av = {0, 0, 0, 0, 0, 0, 0, 0};
    if (s_sp < S && sy >= 0 && sy < SHW && sx >= 0 && sx < SHW)
      av = *(const bf16x8*)(inb + (size_t)(sy * SHW + sx) * CIN + c00 + sch);
    return av;
  };

  {
    bf16x8 av = loadA(0);
    bf16x8 wv = *(const bf16x8*)(wrow + sch);
    *(bf16x8*)&As[0][srow][sch] = av;
    *(bf16x8*)&Bs[0][srow][sch] = wv;
  }
  __syncthreads();
  int cur = 0;
  for (int kt = 0; kt < NS; ++kt) {
    bf16x8 avn, wvn;
    if (kt + 1 < NS) {
      avn = loadA(kt + 1);
      wvn = *(const bf16x8*)(wrow + (kt + 1) * 32 + sch);
    }
    bf16x8 a0 = *(const bf16x8*)&As[cur][wm * 32 + lr][lk];
    bf16x8 a1 = *(const bf16x8*)&As[cur][wm * 32 + 16 + lr][lk];
    bf16x8 b0 = *(const bf16x8*)&Bs[cur][wn * 32 + lr][lk];
    bf16x8 b1 = *(const bf16x8*)&Bs[cur][wn * 32 + 16 + lr][lk];
    acc00 = __builtin_amdgcn_mfma_f32_16x16x32_bf16(a0, b0, acc00, 0, 0, 0);
    acc01 = __builtin_amdgcn_mfma_f32_16x16x32_bf16(a0, b1, acc01, 0, 0, 0);
    acc10 = __builtin_amdgcn_mfma_f32_16x16x32_bf16(a1, b0, acc10, 0, 0, 0);
    acc11 = __builtin_amdgcn_mfma_f32_16x16x32_bf16(a1, b1, acc11, 0, 0, 0);
    if (kt + 1 < NS) {
      *(bf16x8*)&As[cur ^ 1][srow][sch] = avn;
      *(bf16x8*)&Bs[cur ^ 1][srow][sch] = wvn;
    }
    __syncthreads();
    cur ^= 1;
  }

  auto emit = [&](const f32x4& a, int mi, int ni) {
    int c = c0 + wn * 32 + ni * 16 + lr;
    float sg = bg[c] * rsqrtf(bv[c] + EPS_);
    float sh = bbeta[c] - bm[c] * sg;
#pragma unroll
    for (int r = 0; r < 4; ++r) {
      int s = s0 + wm * 32 + mi * 16 + (lane >> 4) * 4 + r;
      if (s < S)
        outp[((size_t)b * S + s) * COUT + c] =
            __float2bfloat16(fmaxf(fmaf(a[r], sg, sh), 0.f));
    }
  };
  emit(acc00, 0, 0);
  emit(acc01, 0, 1);
  emit(acc10, 1, 0);
  emit(acc11, 1, 1);
}

template <int SHW, int C>
__global__ __launch_bounds__(256) void k_convT_mfma(
    const bf16* __restrict__ in, const bf16* __restrict__ wt,
    const float* __restrict__ bias, bf16* __restrict__ outp) {
  constexpr int S = SHW * SHW;
  constexpr int NS = C / 32;
  const int b = blockIdx.z;
  const int ij = blockIdx.y & 3;
  const int c0 = (blockIdx.y >> 2) * 64;
  const int s0 = blockIdx.x * 64;
  __shared__ __align__(16) short As[2][64][40];
  __shared__ __align__(16) short Bs[2][64][40];
  const int t = threadIdx.x;
  const int lane = t & 63;
  const int wm = (t >> 7) & 1;
  const int wn = (t >> 6) & 1;
  const int srow = t >> 2;
  const int sch = (t & 3) * 8;
  const int s_sp = s0 + srow;
  const bf16* arow = in + ((size_t)b * S + s_sp) * C;
  const bf16* wrow = wt + (size_t)ij * C * C + (size_t)(c0 + srow) * C;
  const int lr = lane & 15;
  const int lk = (lane >> 4) * 8;

  f32x4 acc00 = {0.f, 0.f, 0.f, 0.f}, acc01 = {0.f, 0.f, 0.f, 0.f};
  f32x4 acc10 = {0.f, 0.f, 0.f, 0.f}, acc11 = {0.f, 0.f, 0.f, 0.f};

  {
    bf16x8 av = {0, 0, 0, 0, 0, 0, 0, 0};
    if (s_sp < S) av = *(const bf16x8*)(arow + sch);
    bf16x8 wv = *(const bf16x8*)(wrow + sch);
    *(bf16x8*)&As[0][srow][sch] = av;
    *(bf16x8*)&Bs[0][srow][sch] = wv;
  }
  __syncthreads();
  int cur = 0;
  for (int kt = 0; kt < NS; ++kt) {
    bf16x8 avn = {0, 0, 0, 0, 0, 0, 0, 0}, wvn;
    if (kt + 1 < NS) {
      if (s_sp < S) avn = *(const bf16x8*)(arow + (kt + 1) * 32 + sch);
      wvn = *(const bf16x8*)(wrow + (kt + 1) * 32 + sch);
    }
    bf16x8 a0 = *(const bf16x8*)&As[cur][wm * 32 + lr][lk];
    bf16x8 a1 = *(const bf16x8*)&As[cur][wm * 32 + 16 + lr][lk];
    bf16x8 b0 = *(const bf16x8*)&Bs[cur][wn * 32 + lr][lk];
    bf16x8 b1 = *(const bf16x8*)&Bs[cur][wn * 32 + 16 + lr][lk];
    acc00 = __builtin_amdgcn_mfma_f32_16x16x32_bf16(a0, b0, acc00, 0, 0, 0);
    acc01 = __builtin_amdgcn_mfma_f32_16x16x32_bf16(a0, b1, acc01, 0, 0, 0);
    acc10 = __builtin_amdgcn_mfma_f32_16x16x32_bf16(a1, b0, acc10, 0, 0, 0);
    acc11 = __builtin_amdgcn_mfma_f32_16x16x32_bf16(a1, b1, acc11, 0, 0, 0);
    if (kt + 1 < NS) {
      *(bf16x8*)&As[cur ^ 1][srow][sch] = avn;
      *(bf16x8*)&Bs[cur ^ 1][srow][sch] = wvn;
    }
    __syncthreads();
    cur ^= 1;
  }

  auto emit = [&](const f32x4& a, int mi, int ni) {
    int c = c0 + wn * 32 + ni * 16 + lr;
    float bj = bias[c];
#pragma unroll
    for (int r = 0; r < 4; ++r) {
      int s = s0 + wm * 32 + mi * 16 + (lane >> 4) * 4 + r;
      if (s < S) {
        int oy = 2 * (s / SHW) + (ij >> 1);
        int ox = 2 * (s % SHW) + (ij & 1);
        outp[((size_t)b * 4 * S + (size_t)oy * (2 * SHW) + ox) * C + c] =
            __float2bfloat16(a[r] + bj);
      }
    }
  };
  emit(acc00, 0, 0);
  emit(acc01, 0, 1);
  emit(acc10, 1, 0);
  emit(acc11, 1, 1);
}

__global__ __launch_bounds__(256) void k_convT_fuse_mfma(
    const bf16* __restrict__ in, const bf16* __restrict__ wt,
    const float* __restrict__ w3, float* __restrict__ l2c) {
  constexpr int SHW = 30, C = 128, S = SHW * SHW;
  constexpr int NS = C / 32;
  const int b = blockIdx.z;
  const int ij = blockIdx.y & 3;
  const int c0 = (blockIdx.y >> 2) * 64;
  const int s0 = blockIdx.x * 64;
  __shared__ __align__(16) short As[2][64][40];
  __shared__ __align__(16) short Bs[2][64][40];
  __shared__ float red0[64][2];
  __shared__ float red1[64][2];
  const int t = threadIdx.x;
  const int lane = t & 63;
  const int wm = (t >> 7) & 1;
  const int wn = (t >> 6) & 1;
  const int srow = t >> 2;
  const int sch = (t & 3) * 8;
  const int s_sp = s0 + srow;
  const bf16* arow = in + ((size_t)b * S + s_sp) * C;
  const bf16* wrow = wt + (size_t)ij * C * C + (size_t)(c0 + srow) * C;
  const int lr = lane & 15;
  const int lk = (lane >> 4) * 8;

  f32x4 acc00 = {0.f, 0.f, 0.f, 0.f}, acc01 = {0.f, 0.f, 0.f, 0.f};
  f32x4 acc10 = {0.f, 0.f, 0.f, 0.f}, acc11 = {0.f, 0.f, 0.f, 0.f};

  {
    bf16x8 av = {0, 0, 0, 0, 0, 0, 0, 0};
    if (s_sp < S) av = *(const bf16x8*)(arow + sch);
    bf16x8 wv = *(const bf16x8*)(wrow + sch);
    *(bf16x8*)&As[0][srow][sch] = av;
    *(bf16x8*)&Bs[0][srow][sch] = wv;
  }
  __syncthreads();
  int cur = 0;
  for (int kt = 0; kt < NS; ++kt) {
    bf16x8 avn = {0, 0, 0, 0, 0, 0, 0, 0}, wvn;
    if (kt + 1 < NS) {
      if (s_sp < S) avn = *(const bf16x8*)(arow + (kt + 1) * 32 + sch);
      wvn = *(const bf16x8*)(wrow + (kt + 1) * 32 + sch);
    }
    bf16x8 a0 = *(const bf16x8*)&As[cur][wm * 32 + lr][lk];
    bf16x8 a1 = *(const bf16x8*)&As[cur][wm * 32 + 16 + lr][lk];
    bf16x8 b0 = *(const bf16x8*)&Bs[cur][wn * 32 + lr][lk];
    bf16x8 b1 = *(const bf16x8*)&Bs[cur][wn * 32 + 16 + lr][lk];
    acc00 = __builtin_amdgcn_mfma_f32_16x16x32_bf16(a0, b0, acc00, 0, 0, 0);
    acc01 = __builtin_amdgcn_mfma_f32_16x16x32_bf16(a0, b1, acc01, 0, 0, 0);
    acc10 = __builtin_amdgcn_mfma_f32_16x16x32_bf16(a1, b0, acc10, 0, 0, 0);
    acc11 = __builtin_amdgcn_mfma_f32_16x16x32_bf16(a1, b1, acc11, 0, 0, 0);
    if (kt + 1 < NS) {
      *(bf16x8*)&As[cur ^ 1][srow][sch] = avn;
      *(bf16x8*)&Bs[cur ^ 1][srow][sch] = wvn;
    }
    __syncthreads();
    cur ^= 1;
  }

  const float w0a = w3[c0 + wn * 32 + lr];
  const float w0b = w3[c0 + wn * 32 + 16 + lr];
  const float w1a = w3[MID_ + c0 + wn * 32 + lr];
  const float w1b = w3[MID_ + c0 + wn * 32 + 16 + lr];
#pragma unroll
  for (int mi = 0; mi < 2; ++mi) {
    f32x4 aa0 = mi ? acc10 : acc00;
    f32x4 aa1 = mi ? acc11 : acc01;
#pragma unroll
    for (int r = 0; r < 4; ++r) {
      float p0 = aa0[r] * w0a + aa1[r] * w0b;
      float p1 = aa0[r] * w1a + aa1[r] * w1b;
      p0 += __shfl_xor(p0, 1); p0 += __shfl_xor(p0, 2);
      p0 += __shfl_xor(p0, 4); p0 += __shfl_xor(p0, 8);
      p1 += __shfl_xor(p1, 1); p1 += __shfl_xor(p1, 2);
      p1 += __shfl_xor(p1, 4); p1 += __shfl_xor(p1, 8);
      if (lr == 0) {
        int rl = wm * 32 + mi * 16 + (lane >> 4) * 4 + r;
        red0[rl][wn] = p0;
        red1[rl][wn] = p1;
      }
    }
  }
  __syncthreads();
  if (t < 64) {
    int s = s0 + t;
    if (s < S) {
      float v0 = red0[t][0] + red0[t][1];
      float v1 = red1[t][0] + red1[t][1];
      int oy = 2 * (s / SHW) + (ij >> 1);
      int ox = 2 * (s % SHW) + (ij & 1);
      int opix = oy * 60 + ox;
      atomicAdd(&l2c[(size_t)b * 7200 + opix], v0);
      atomicAdd(&l2c[(size_t)b * 7200 + 3600 + opix], v1);
    }
  }
}

// ---------------- l2c init ----------------
__global__ void k_l2cinit(const float* __restrict__ lt2b, const float* __restrict__ w3,
                          const float* __restrict__ b3, float* __restrict__ l2c) {
  __shared__ float ini[2];
  int t = threadIdx.x;
  if (t < 2) {
    float s = b3[t];
    for (int ci = 0; ci < MID_; ++ci) s = fmaf(lt2b[ci], w3[t * MID_ + ci], s);
    ini[t] = s;
  }
  __syncthreads();
  int i = blockIdx.x * 256 + t;
  if (i < 7200) l2c[(size_t)blockIdx.y * 7200 + i] = ini[i / 3600];
}

// ---------------- patch head ----------------
__global__ __launch_bounds__(256) void k_patch(const float* __restrict__ l2c,
    const float* __restrict__ residual, float* __restrict__ out_ev,
    float* __restrict__ out_pl) {
  const int b = blockIdx.x;
  __shared__ float sm0[3600];
  __shared__ float sm1[3600];
  for (int i = threadIdx.x; i < 3600; i += 256) {
    sm0[i] = l2c[(size_t)b * 7200 + i];
    sm1[i] = l2c[(size_t)b * 7200 + 3600 + i];
  }
  __syncthreads();
  const int t = threadIdx.x;
  if (t >= 225) return;
  const int py = t / 15, px = t % 15;
  const float cy = 16.f * py + 7.5f;
  const float cx = 16.f * px + 7.5f;
  const int ky_lo = max(0, 16 * py - 8), ky_hi = min(239, 16 * py + 23);
  const int kx_lo = max(0, 16 * px - 8), kx_hi = min(239, 16 * px + 23);
  float acc0 = 0.f, acc1 = 0.f, wsum = 0.f;
  for (int ky = ky_lo; ky <= ky_hi; ++ky) {
    float wy = 1.f - fabsf((float)ky - cy) * 0.0625f;
    float c60y = 0.25f * ky - 0.375f;
    int jy = (int)floorf(c60y);
    float fy = c60y - (float)jy;
    int jy0 = max(jy, 0), jy1 = min(jy + 1, 59);
    for (int kx = kx_lo; kx <= kx_hi; ++kx) {
      float wx = 1.f - fabsf((float)kx - cx) * 0.0625f;
      float w = wy * wx;
      float c60x = 0.25f * kx - 0.375f;
      int jx = (int)floorf(c60x);
      float fx = c60x - (float)jx;
      int jx0 = max(jx, 0), jx1 = min(jx + 1, 59);
      float v0 = (1.f - fy) * ((1.f - fx) * sm0[jy0 * 60 + jx0] + fx * sm0[jy0 * 60 + jx1])
               + fy * ((1.f - fx) * sm0[jy1 * 60 + jx0] + fx * sm0[jy1 * 60 + jx1]);
      float v1 = (1.f - fy) * ((1.f - fx) * sm1[jy0 * 60 + jx0] + fx * sm1[jy0 * 60 + jx1])
               + fy * ((1.f - fx) * sm1[jy1 * 60 + jx0] + fx * sm1[jy1 * 60 + jx1]);
      acc0 = fmaf(w, v0, acc0);
      acc1 = fmaf(w, v1, acc1);
      wsum += w;
    }
  }
  float p0 = acc0 / wsum, p1 = acc1 / wsum;
  float logit = p1 - p0;
  float score1 = 1.0f / (1.0f + expf(p0 - p1));
  float ev = 0.5f * residual[b * N_ + t] + 0.5f * score1;
  out_pl[b * N_ + t] = logit;
  out_ev[b * N_ + t] = ev;
}

// ---------------- upsample 60->240 bilinear ----------------
__global__ __launch_bounds__(256) void k_up(const float* __restrict__ l2c,
                                            float* __restrict__ out_l2c,
                                            float* __restrict__ out_ls) {
  const int b = blockIdx.y;
  const int pix = blockIdx.x * 256 + threadIdx.x;
  const int y = pix / 240, x = pix % 240;
  float sy = 0.25f * y - 0.375f;
  int ky = (int)floorf(sy);
  float fy = sy - (float)ky;
  float sx = 0.25f * x - 0.375f;
  int kx = (int)floorf(sx);
  float fx = sx - (float)kx;
  int ky0 = max(ky, 0), ky1 = min(ky + 1, 59);
  int kx0 = max(kx, 0), kx1 = min(kx + 1, 59);
  float v[2];
#pragma unroll
  for (int c = 0; c < 2; ++c) {
    const float* base = l2c + ((size_t)b * 2 + c) * 3600;
    float top = (1.f - fx) * base[ky0 * 60 + kx0] + fx * base[ky0 * 60 + kx1];
    float bot = (1.f - fx) * base[ky1 * 60 + kx0] + fx * base[ky1 * 60 + kx1];
    v[c] = (1.f - fy) * top + fy * bot;
  }
  float s1 = 1.f / (1.f + expf(v[0] - v[1]));
  float s0 = 1.f / (1.f + expf(v[1] - v[0]));
  size_t o0 = ((size_t)b * 2 + 0) * 57600 + pix;
  size_t o1 = ((size_t)b * 2 + 1) * 57600 + pix;
  out_l2c[o0] = v[0];
  out_l2c[o1] = v[1];
  out_ls[o0] = s0;
  out_ls[o1] = s1;
}

// ---------------- fusion stats ----------------
__global__ __launch_bounds__(256) void k_fusion(const bf16* __restrict__ cmap,
                                                float* __restrict__ gfeat) {
  int wid = ((blockIdx.x * 256 + threadIdx.x) >> 6);
  int lane = threadIdx.x & 63;
  if (wid >= B_ * D_) return;
  int b = wid / D_, d = wid % D_;
  const bf16* base = cmap + (size_t)b * N_ * D_ + d;
  float v[4];
  bool alive[4];
  float sum = 0.f;
#pragma unroll
  for (int r = 0; r < 4; ++r) {
    int n = lane + r * 64;
    bool ok = (n < N_);
    v[r] = ok ? __bfloat162float(base[(size_t)n * D_]) : -INFINITY;
    alive[r] = ok;
    if (ok) sum += v[r];
  }
  for (int o = 32; o > 0; o >>= 1) sum += __shfl_xor(sum, o);
  float topsum = 0.f;
  for (int it = 0; it < 10; ++it) {
    float lm = -INFINITY;
    int ls = -1;
#pragma unroll
    for (int r = 0; r < 4; ++r)
      if (alive[r] && v[r] > lm) { lm = v[r]; ls = r; }
    float wm = lm;
    for (int o = 32; o > 0; o >>= 1) wm = fmaxf(wm, __shfl_xor(wm, o));
    topsum += wm;
    u64 ball = __ballot(lm == wm);
    int owner = __ffsll((long long)ball) - 1;
    if (lane == owner && ls >= 0) alive[ls] = false;
  }
  if (lane == 0) gfeat[wid] = 0.5f * (sum / 225.0f + topsum * 0.1f);
}

// ---------------- fused FC head ----------------
__global__ __launch_bounds__(256) void k_fc(const float* __restrict__ gfeat,
    const float* __restrict__ g1w, const float* __restrict__ bg1,
    const float* __restrict__ bb1, const float* __restrict__ bm1,
    const float* __restrict__ bv1, const float* __restrict__ g2w,
    const float* __restrict__ bg2, const float* __restrict__ bb2,
    const float* __restrict__ bm2, const float* __restrict__ bv2,
    const float* __restrict__ g3w, float* __restrict__ out_gl,
    float* __restrict__ out_g2c) {
  __shared__ float gf[D_];
  __shared__ float h1s[H_];
  __shared__ float h2s[MID_];
  __shared__ float g2cs[2];
  const int b = blockIdx.x;
  const int t = threadIdx.x;
  for (int i = t; i < D_; i += 256) gf[i] = gfeat[b * D_ + i];
  __syncthreads();
  {
    float a = 0.f;
    const float* w = g1w + (size_t)t * D_;
    for (int d = 0; d < D_; ++d) a = fmaf(gf[d], w[d], a);
    float s = bg1[t] * rsqrtf(bv1[t] + EPS_);
    h1s[t] = fmaxf((a - bm1[t]) * s + bb1[t], 0.f);
  }
  __syncthreads();
  if (t < MID_) {
    float a = 0.f;
    const float* w = g2w + (size_t)t * H_;
    for (int k = 0; k < H_; ++k) a = fmaf(h1s[k], w[k], a);
    float s = bg2[t] * rsqrtf(bv2[t] + EPS_);
    h2s[t] = fmaxf((a - bm2[t]) * s + bb2[t], 0.f);
  }
  __syncthreads();
  if (t < 2) {
    float a = 0.f;
    const float* w = g3w + (size_t)t * MID_;
    for (int k = 0; k < MID_; ++k) a = fmaf(h2s[k], w[k], a);
    g2cs[t] = a;
    out_g2c[b * 2 + t] = a;
  }
  __syncthreads();
  if (t == 0) out_gl[b] = g2cs[1] - g2cs[0];
}

// ================= host =================
extern "C" void kernel_launch(void* const* d_in, const int* in_sizes, int n_in,
                              void* d_out, int out_size, void* d_ws, size_t ws_size,
                              hipStream_t stream) {
  (void)in_sizes; (void)n_in; (void)out_size; (void)ws_size;
  const float* query = (const float*)d_in[0];
  const float* prompt = (const float*)d_in[1];
  const float* bns_g = (const float*)d_in[2];
  const float* bns_b = (const float*)d_in[3];
  const float* bns_m = (const float*)d_in[4];
  const float* bns_v = (const float*)d_in[5];
  const float* lc1_w = (const float*)d_in[6];
  const float* lbn1_g = (const float*)d_in[7];
  const float* lbn1_b = (const float*)d_in[8];
  const float* lbn1_m = (const float*)d_in[9];
  const float* lbn1_v = (const float*)d_in[10];
  const float* lt1_w = (const float*)d_in[11];
  const float* lt1_b = (const float*)d_in[12];
  const float* lc2_w = (const float*)d_in[13];
  const float* lbn2_g = (const float*)d_in[14];
  const float* lbn2_b = (const float*)d_in[15];
  const float* lbn2_m = (const float*)d_in[16];
  const float* lbn2_v = (const float*)d_in[17];
  const float* lt2_w = (const float*)d_in[18];
  const float* lt2_b = (const float*)d_in[19];
  const float* lc3_w = (const float*)d_in[20];
  const float* lc3_b = (const float*)d_in[21];
  const float* g1_w = (const float*)d_in[22];
  const float* gbn1_g = (const float*)d_in[23];
  const float* gbn1_b = (const float*)d_in[24];
  const float* gbn1_m = (const float*)d_in[25];
  const float* gbn1_v = (const float*)d_in[26];
  const float* g2_w = (const float*)d_in[27];
  const float* gbn2_g = (const float*)d_in[28];
  const float* gbn2_b = (const float*)d_in[29];
  const float* gbn2_m = (const float*)d_in[30];
  const float* gbn2_v = (const float*)d_in[31];
  const float* g3_w = (const float*)d_in[32];

  float* ob = (float*)d_out;  // output is float32
  char* ob_c = (char*)d_out;
  char* ws = (char*)d_ws;
  // --- workspace (~8.5 MB) ---
  u64* keys = (u64*)(ws + 0);                    // 57,600 B
  float* qinv = (float*)(ws + 57600);            // 28,800
  float* pinv = (float*)(ws + 86400);            // 230,400
  float* residual = (float*)(ws + 316800);       // 57,600
  int* idxbuf = (int*)(ws + 374400);             // 28,800
  float* gfeat = (float*)(ws + 403200);          // 98,304
  float* l2c = (float*)(ws + 501504);            // 1,843,200
  bf16* wt1 = (bf16*)(ws + 2344704);             // 3,538,944
  bf16* wtT1 = (bf16*)(ws + 5883648);            // 524,288
  bf16* wt2 = (bf16*)(ws + 6407936);             // 589,824
  bf16* wtT2 = (bf16*)(ws + 6997760);            // 131,072
  unsigned* flags = (unsigned*)(ws + 7128832);   // 28,800
  u64* pkeys = (u64*)(ws + 7157632);             // 864,000
  float* pmax2 = (float*)(ws + 8021632);         // 432,000 -> end 8,453,632

  // output offsets in f32 elements (return order: ev, pl, gl, g2c, l2c, ls, res, idx)
  const size_t OFF_EV = 0;
  const size_t OFF_PL = 14400;
  const size_t OFF_GL = 28800;
  const size_t OFF_G2C = 28864;
  const size_t OFF_L2C = 28992;
  const size_t OFF_LS = 7401792;
  const size_t OFF_RES = 14774592;
  const size_t OFF_IDX = 14788992;

  // bf16 conv scratch packed into the BYTE range of the l2c/ls chunks
  bf16* cmap = (bf16*)(ob_c + 115968);
  bf16* x1 = (bf16*)(ob_c + 11175168);
  bf16* y1 = (bf16*)(ob_c + 14861568);
  bf16* x2 = (bf16*)(ob_c + 29607168);

  // ---------- phase A ----------
  for (int l = 0; l < L_; ++l) {
    const float* q = query + (size_t)l * B_ * N_ * D_;
    const float* p = prompt + (size_t)l * B_ * M_ * D_;
    float* out_gl = ob + OFF_GL + (size_t)l * B_;
    float* out_g2c = ob + OFF_G2C + (size_t)l * B_ * 2;
    float* out_res = ob + OFF_RES + (size_t)l * B_ * N_;
    float* out_idx = ob + OFF_IDX + (size_t)l * B_ * N_;
    float* res_l = residual + (size_t)l * B_ * N_;
    float* l2c_l = l2c + (size_t)l * B_ * 7200;

    k_norms<<<dim3(B_ * (N_ + M_)), dim3(256), 0, stream>>>(q, p, qinv, pinv);
    k_sim3<<<dim3(15, B_), dim3(256), 0, stream>>>(q, p, qinv, pinv, pkeys, pmax2);
    k_reduce<<<dim3(29), dim3(256), 0, stream>>>(pkeys, pmax2, keys, flags);
    k_exact<<<dim3(B_ * N_, 15), dim3(256), 0, stream>>>(q, p, qinv, pinv, flags, keys);
    k_decode<<<dim3(29), dim3(256), 0, stream>>>(keys, res_l, idxbuf, out_res, out_idx);
    k_cmap<<<dim3(B_ * N_), dim3(256), 0, stream>>>(q, p, idxbuf,
        bns_g + l * D_, bns_b + l * D_, bns_m + l * D_, bns_v + l * D_, cmap);
    k_fusion<<<dim3(B_ * D_ / 4), dim3(256), 0, stream>>>(cmap, gfeat);
    k_fc<<<dim3(B_), dim3(256), 0, stream>>>(gfeat,
        g1_w + (size_t)l * H_ * D_, gbn1_g + l * H_, gbn1_b + l * H_, gbn1_m + l * H_, gbn1_v + l * H_,
        g2_w + (size_t)l * MID_ * H_, gbn2_g + l * MID_, gbn2_b + l * MID_, gbn2_m + l * MID_, gbn2_v + l * MID_,
        g3_w + (size_t)l * 2 * MID_, out_gl, out_g2c);
    k_prepw<<<dim3(9344), dim3(256), 0, stream>>>(
        lc1_w + (size_t)l * H_ * D_ * 9, lt1_w + (size_t)l * H_ * H_ * 4,
        lc2_w + (size_t)l * MID_ * H_ * 9, lt2_w + (size_t)l * MID_ * MID_ * 4,
        wt1, wtT1, wt2, wtT2);
    k_l2cinit<<<dim3(29, B_), dim3(256), 0, stream>>>(lt2_b + l * MID_,
        lc3_w + (size_t)l * 2 * MID_, lc3_b + l * 2, l2c_l);
    k_conv3x3_mfma<15, 768, 256><<<dim3(4, 4, B_), dim3(256), 0, stream>>>(cmap, wt1,
        lbn1_g + l * H_, lbn1_b + l * H_, lbn1_m + l * H_, lbn1_v + l * H_, x1);
    k_convT_mfma<15, 256><<<dim3(4, 16, B_), dim3(256), 0, stream>>>(x1, wtT1,
        lt1_b + l * H_, y1);
    k_conv3x3_mfma<30, 256, 128><<<dim3(15, 2, B_), dim3(256), 0, stream>>>(y1, wt2,
        lbn2_g + l * MID_, lbn2_b + l * MID_, lbn2_m + l * MID_, lbn2_v + l * MID_, x2);
    k_convT_fuse_mfma<<<dim3(15, 8, B_), dim3(256), 0, stream>>>(x2, wtT2,
        lc3_w + (size_t)l * 2 * MID_, l2c_l);
  }

  // ---------- phase B ----------
  for (int l = 0; l < L_; ++l) {
    float* out_ev = ob + OFF_EV + (size_t)l * B_ * N_;
    float* out_pl = ob + OFF_PL + (size_t)l * B_ * N_;
    float* out_l2c = ob + OFF_L2C + (size_t)l * B_ * 2 * 57600;
    float* out_ls = ob + OFF_LS + (size_t)l * B_ * 2 * 57600;
    float* res_l = residual + (size_t)l * B_ * N_;
    float* l2c_l = l2c + (size_t)l * B_ * 7200;
    k_patch<<<dim3(B_), dim3(256), 0, stream>>>(l2c_l, res_l, out_ev, out_pl);
    k_up<<<dim3(225, B_), dim3(256), 0, stream>>>(l2c_l, out_l2c, out_ls);
  }
}